// Round 8
// baseline (371.148 us; speedup 1.0000x reference)
//
#include <hip/hip_runtime.h>
#include <hip/hip_bf16.h>

constexpr int HEADS  = 4;
constexpr int HID    = 64;
constexpr int IN_F   = 128;
constexpr int GROUPS = 64;
constexpr float NEG_SLOPE = 0.2f;
constexpr float EPS_SM    = 1e-16f;

typedef short bf16x8 __attribute__((ext_vector_type(8)));
typedef float f32x4  __attribute__((ext_vector_type(4)));

static __device__ __forceinline__ float lrelu(float x) { return x >= 0.f ? x : NEG_SLOPE * x; }
static __device__ __forceinline__ float elu1(float x)  { return x > 0.f ? x : expm1f(x); }

static __device__ __forceinline__ float bf2f(unsigned int u) {
  union { unsigned int i; float f; } x; x.i = u << 16; return x.f;
}
static __device__ __forceinline__ unsigned short f2bf(float f) {
  union { float f; unsigned int i; } x; x.f = f;
  unsigned int lsb = (x.i >> 16) & 1u;
  x.i += 0x7fffu + lsb;
  return (unsigned short)(x.i >> 16);
}

// ---- prep: W1T_hi/lo[256][128] (bf16) from W1[128][256] fp32 ----
__global__ __launch_bounds__(256) void prep_w1_kernel(
    const float* __restrict__ W1, unsigned short* __restrict__ WThi,
    unsigned short* __restrict__ WTlo) {
  const int k = blockIdx.x;            // 0..127
  const int n = threadIdx.x;           // 0..255
  const float w = W1[(size_t)k * 256 + n];
  const unsigned short hi = f2bf(w);
  const float r = w - bf2f(hi);
  WThi[(size_t)n * 128 + k] = hi;
  WTlo[(size_t)n * 128 + k] = f2bf(r);
}

// ---- GEMM1 via MFMA + fused alpha1: h1b[N,256](bf16) = x @ W1 ; as1/ad1[N,4] ----
// 4 waves/block, 64 rows/block; wave = 16 rows x 256 cols; K=128 in 4 steps of 32.
// hi/lo split keeps fp32-equivalent accuracy (3 MFMAs per tile per k-step).
__global__ __launch_bounds__(256) void gemm1_mfma_kernel(
    const float* __restrict__ x,
    const unsigned short* __restrict__ WThi, const unsigned short* __restrict__ WTlo,
    const float* __restrict__ att_s, const float* __restrict__ att_d,
    unsigned short* __restrict__ h1b, float* __restrict__ as1, float* __restrict__ ad1, int N) {
  const int lane = threadIdx.x & 63;
  const int wid  = threadIdx.x >> 6;           // 0..3
  const int row0 = blockIdx.x * 64 + wid * 16; // wave's 16-row strip
  const int fr = lane & 15;                    // frag row (A) / col (B/C)
  const int fg = lane >> 4;                    // k-group 0..3 (A/B), row-group (C)
  const int myrow = row0 + fr;
  const bool rok = myrow < N;

  f32x4 acc[16];
#pragma unroll
  for (int n = 0; n < 16; n++) acc[n] = (f32x4){0.f, 0.f, 0.f, 0.f};

#pragma unroll
  for (int ks = 0; ks < 4; ks++) {
    const int kbase = ks * 32 + fg * 8;
    float xv[8];
    if (rok) {
      const float4 a = *reinterpret_cast<const float4*>(&x[(size_t)myrow * IN_F + kbase]);
      const float4 b = *reinterpret_cast<const float4*>(&x[(size_t)myrow * IN_F + kbase + 4]);
      xv[0]=a.x; xv[1]=a.y; xv[2]=a.z; xv[3]=a.w;
      xv[4]=b.x; xv[5]=b.y; xv[6]=b.z; xv[7]=b.w;
    } else {
#pragma unroll
      for (int j = 0; j < 8; j++) xv[j] = 0.f;
    }
    bf16x8 ahi, alo;
#pragma unroll
    for (int j = 0; j < 8; j++) {
      const unsigned short h = f2bf(xv[j]);
      const float r = xv[j] - bf2f(h);
      ahi[j] = (short)h;
      alo[j] = (short)f2bf(r);
    }
#pragma unroll
    for (int n = 0; n < 16; n++) {
      const size_t boff = (size_t)(n * 16 + fr) * IN_F + kbase;
      const bf16x8 bhi = *reinterpret_cast<const bf16x8*>(&WThi[boff]);
      const bf16x8 blo = *reinterpret_cast<const bf16x8*>(&WTlo[boff]);
      acc[n] = __builtin_amdgcn_mfma_f32_16x16x32_bf16(ahi, bhi, acc[n], 0, 0, 0);
      acc[n] = __builtin_amdgcn_mfma_f32_16x16x32_bf16(alo, bhi, acc[n], 0, 0, 0);
      acc[n] = __builtin_amdgcn_mfma_f32_16x16x32_bf16(ahi, blo, acc[n], 0, 0, 0);
    }
  }

  // fused alpha1: per-row dots with att vectors. C/D: col = n*16+fr, row = row0+fg*4+r.
  float psS[4][4], psD[4][4];
#pragma unroll
  for (int h = 0; h < 4; h++)
#pragma unroll
    for (int r = 0; r < 4; r++) { psS[h][r] = 0.f; psD[h][r] = 0.f; }
#pragma unroll
  for (int n = 0; n < 16; n++) {
    const int col = n * 16 + fr;
    const float as_ = att_s[col];
    const float ad_ = att_d[col];
    const int h = n >> 2;
#pragma unroll
    for (int r = 0; r < 4; r++) {
      psS[h][r] = fmaf(acc[n][r], as_, psS[h][r]);
      psD[h][r] = fmaf(acc[n][r], ad_, psD[h][r]);
    }
  }
#pragma unroll
  for (int h = 0; h < 4; h++)
#pragma unroll
    for (int r = 0; r < 4; r++)
#pragma unroll
      for (int o = 8; o > 0; o >>= 1) {
        psS[h][r] += __shfl_xor(psS[h][r], o, 64);
        psD[h][r] += __shfl_xor(psD[h][r], o, 64);
      }
  if (fr == 0) {
#pragma unroll
    for (int r = 0; r < 4; r++) {
      const int row = row0 + fg * 4 + r;
      if (row < N) {
#pragma unroll
        for (int h = 0; h < 4; h++) {
          as1[(size_t)row * 4 + h] = psS[h][r];
          ad1[(size_t)row * 4 + h] = psD[h][r];
        }
      }
    }
  }
  // bf16 store of h1
#pragma unroll
  for (int r = 0; r < 4; r++) {
    const int row = row0 + fg * 4 + r;
    if (row < N) {
#pragma unroll
      for (int n = 0; n < 16; n++)
        h1b[(size_t)row * 256 + n * 16 + fr] = f2bf(acc[n][r]);
    }
  }
}

// ---------------- CSR build ----------------
__global__ __launch_bounds__(256) void hist_kernel(const int* __restrict__ dst, int* __restrict__ cnt, int E) {
  const int e = blockIdx.x * 256 + threadIdx.x;
  if (e < E) atomicAdd(&cnt[dst[e]], 1);
}

__global__ __launch_bounds__(256) void block_reduce_kernel(
    const int* __restrict__ cnt, int* __restrict__ bsum, int N) {
  const int i = blockIdx.x * 256 + threadIdx.x;
  int v = (i < N) ? cnt[i] : 0;
#pragma unroll
  for (int o = 32; o > 0; o >>= 1) v += __shfl_xor(v, o, 64);
  __shared__ int ws_[4];
  if ((threadIdx.x & 63) == 0) ws_[threadIdx.x >> 6] = v;
  __syncthreads();
  if (threadIdx.x == 0)
    bsum[blockIdx.x] = ws_[0] + ws_[1] + ws_[2] + ws_[3];
}

__global__ __launch_bounds__(256) void bsum_scan_kernel(
    int* __restrict__ bsum, int* __restrict__ boff, int NB) {
  __shared__ int sdata[256];
  const int t = threadIdx.x;
  int v = (t < NB) ? bsum[t] : 0;
  sdata[t] = v;
  __syncthreads();
  for (int o = 1; o < 256; o <<= 1) {
    int x = (t >= o) ? sdata[t - o] : 0;
    __syncthreads();
    sdata[t] += x;
    __syncthreads();
  }
  if (t < NB) boff[t] = sdata[t] - v;   // exclusive
}

__global__ __launch_bounds__(256) void block_scan_kernel(
    const int* __restrict__ cnt, const int* __restrict__ boff,
    int* __restrict__ row_start, int* __restrict__ cursor, int N) {
  __shared__ int sdata[256];
  const int t = threadIdx.x;
  const int i = blockIdx.x * 256 + t;
  int v = (i < N) ? cnt[i] : 0;
  sdata[t] = v;
  __syncthreads();
  for (int o = 1; o < 256; o <<= 1) {
    int x = (t >= o) ? sdata[t - o] : 0;
    __syncthreads();
    sdata[t] += x;
    __syncthreads();
  }
  if (i < N) {
    const int rs = boff[blockIdx.x] + sdata[t] - v;
    row_start[i] = rs;
    cursor[i] = rs;
    if (i == N - 1) row_start[N] = rs + v;
  }
}

__global__ __launch_bounds__(256) void scatter_kernel(
    const int* __restrict__ src, const int* __restrict__ dst,
    int* __restrict__ cursor, int* __restrict__ csr_src, int E) {
  const int e = blockIdx.x * 256 + threadIdx.x;
  if (e < E) {
    const int d = dst[e];
    const int pos = atomicAdd(&cursor[d], 1);
    csr_src[pos] = src[e];
  }
}

// ---- edge weights conv1: one pass (scores bounded, max-shift unnecessary) ----
__global__ __launch_bounds__(256) void edge_w1_kernel(
    const float* __restrict__ as1, const float* __restrict__ ad1,
    const int* __restrict__ row_start, const int* __restrict__ csr_src,
    float* __restrict__ w1, float* __restrict__ wself, float* __restrict__ winv, int N) {
  const int sl = threadIdx.x & 31;
  const int v = blockIdx.x * 8 + (threadIdx.x >> 5);
  if (v >= N) return;
  const int rs = row_start[v], re = row_start[v + 1];
  const float4 adv = *reinterpret_cast<const float4*>(&ad1[(size_t)v * 4]);
  const float4 asv = *reinterpret_cast<const float4*>(&as1[(size_t)v * 4]);
  const float* adp = reinterpret_cast<const float*>(&adv);
  const float* asp = reinterpret_cast<const float*>(&asv);
  float den[HEADS] = {0.f, 0.f, 0.f, 0.f};
  for (int k = rs + sl; k < re; k += 32) {
    const int s = csr_src[k];
    const float4 av = *reinterpret_cast<const float4*>(&as1[(size_t)s * 4]);
    const float* ap = reinterpret_cast<const float*>(&av);
    float4 wv;
    float* wp = reinterpret_cast<float*>(&wv);
#pragma unroll
    for (int h = 0; h < HEADS; h++) {
      const float w = __expf(lrelu(ap[h] + adp[h]));
      wp[h] = w;
      den[h] += w;
    }
    *reinterpret_cast<float4*>(&w1[(size_t)k * 4]) = wv;
  }
#pragma unroll
  for (int h = 0; h < HEADS; h++)
#pragma unroll
    for (int o = 16; o > 0; o >>= 1) den[h] += __shfl_xor(den[h], o, 64);
  if (sl == 0) {
    float4 wsv, wiv;
    float* wsp = reinterpret_cast<float*>(&wsv);
    float* wip = reinterpret_cast<float*>(&wiv);
#pragma unroll
    for (int h = 0; h < HEADS; h++) {
      const float ws_ = __expf(lrelu(asp[h] + adp[h]));
      wsp[h] = ws_;
      wip[h] = 1.f / (den[h] + ws_ + EPS_SM);
    }
    *reinterpret_cast<float4*>(&wself[(size_t)v * 4]) = wsv;
    *reinterpret_cast<float4*>(&winv[(size_t)v * 4]) = wiv;
  }
}

// ---- edge weights conv2 (1 head): one pass ----
__global__ __launch_bounds__(256) void edge_w2_kernel(
    const float* __restrict__ as2, const float* __restrict__ ad2,
    const int* __restrict__ row_start, const int* __restrict__ csr_src,
    float* __restrict__ w2, float* __restrict__ wself2, float* __restrict__ winv2, int N) {
  const int sl = threadIdx.x & 31;
  const int v = blockIdx.x * 8 + (threadIdx.x >> 5);
  if (v >= N) return;
  const int rs = row_start[v], re = row_start[v + 1];
  const float adv = ad2[v];
  float den = 0.f;
  for (int k = rs + sl; k < re; k += 32) {
    const float w = __expf(lrelu(as2[csr_src[k]] + adv));
    w2[k] = w;
    den += w;
  }
#pragma unroll
  for (int o = 16; o > 0; o >>= 1) den += __shfl_xor(den, o, 64);
  if (sl == 0) {
    const float ws_ = __expf(lrelu(as2[v] + adv));
    wself2[v] = ws_;
    winv2[v] = 1.f / (den + ws_ + EPS_SM);
  }
}

// ---- gather1: bf16 gather, 4-edge chunks, one-chunk-ahead meta prefetch ----
__global__ __launch_bounds__(256) void gather1w_kernel(
    const unsigned short* __restrict__ h1b, const float* __restrict__ w1,
    const float* __restrict__ wself, const float* __restrict__ winv,
    const float* __restrict__ b1, const int* __restrict__ row_start,
    const int* __restrict__ csr_src, unsigned short* __restrict__ hmidb, int N) {
  const int lane = threadIdx.x & 63;
  const int v = blockIdx.x * 4 + (threadIdx.x >> 6);
  if (v >= N) return;
  const int hd = lane >> 4;       // head of this lane's 4 channels
  const int rs = row_start[v], re = row_start[v + 1];
  const float ws = wself[(size_t)v * 4 + hd];
  const ushort4 sv = reinterpret_cast<const ushort4*>(h1b + (size_t)v * 256)[lane];
  float4 acc;
  acc.x = ws * bf2f(sv.x); acc.y = ws * bf2f(sv.y);
  acc.z = ws * bf2f(sv.z); acc.w = ws * bf2f(sv.w);
  if (rs < re) {
    const int rl = re - 1;
    int k = rs;
    int s0 = csr_src[k];
    int s1 = csr_src[min(k + 1, rl)];
    int s2 = csr_src[min(k + 2, rl)];
    int s3 = csr_src[min(k + 3, rl)];
    float y0 = w1[(size_t)k * 4 + hd];
    float t1 = w1[(size_t)min(k + 1, rl) * 4 + hd];
    float t2 = w1[(size_t)min(k + 2, rl) * 4 + hd];
    float t3 = w1[(size_t)min(k + 3, rl) * 4 + hd];
    float y1 = (k + 1 < re) ? t1 : 0.f;
    float y2 = (k + 2 < re) ? t2 : 0.f;
    float y3 = (k + 3 < re) ? t3 : 0.f;
    while (k < re) {
      const int kn = k + 4;
      const ushort4 f0 = reinterpret_cast<const ushort4*>(h1b + (size_t)s0 * 256)[lane];
      const ushort4 f1 = reinterpret_cast<const ushort4*>(h1b + (size_t)s1 * 256)[lane];
      const ushort4 f2 = reinterpret_cast<const ushort4*>(h1b + (size_t)s2 * 256)[lane];
      const ushort4 f3 = reinterpret_cast<const ushort4*>(h1b + (size_t)s3 * 256)[lane];
      const int kc0 = min(kn, rl), kc1 = min(kn + 1, rl), kc2 = min(kn + 2, rl), kc3 = min(kn + 3, rl);
      const int n0 = csr_src[kc0];
      const int n1 = csr_src[kc1];
      const int n2 = csr_src[kc2];
      const int n3 = csr_src[kc3];
      const float u0 = w1[(size_t)kc0 * 4 + hd];
      const float u1 = w1[(size_t)kc1 * 4 + hd];
      const float u2 = w1[(size_t)kc2 * 4 + hd];
      const float u3 = w1[(size_t)kc3 * 4 + hd];
      acc.x = fmaf(y0, bf2f(f0.x), acc.x); acc.y = fmaf(y0, bf2f(f0.y), acc.y);
      acc.z = fmaf(y0, bf2f(f0.z), acc.z); acc.w = fmaf(y0, bf2f(f0.w), acc.w);
      acc.x = fmaf(y1, bf2f(f1.x), acc.x); acc.y = fmaf(y1, bf2f(f1.y), acc.y);
      acc.z = fmaf(y1, bf2f(f1.z), acc.z); acc.w = fmaf(y1, bf2f(f1.w), acc.w);
      acc.x = fmaf(y2, bf2f(f2.x), acc.x); acc.y = fmaf(y2, bf2f(f2.y), acc.y);
      acc.z = fmaf(y2, bf2f(f2.z), acc.z); acc.w = fmaf(y2, bf2f(f2.w), acc.w);
      acc.x = fmaf(y3, bf2f(f3.x), acc.x); acc.y = fmaf(y3, bf2f(f3.y), acc.y);
      acc.z = fmaf(y3, bf2f(f3.z), acc.z); acc.w = fmaf(y3, bf2f(f3.w), acc.w);
      s0 = n0; s1 = n1; s2 = n2; s3 = n3;
      y0 = (kn     < re) ? u0 : 0.f;
      y1 = (kn + 1 < re) ? u1 : 0.f;
      y2 = (kn + 2 < re) ? u2 : 0.f;
      y3 = (kn + 3 < re) ? u3 : 0.f;
      k = kn;
    }
  }
  const float wi = winv[(size_t)v * 4 + hd];
  const int c0 = lane * 4;
  const float4 bv = *reinterpret_cast<const float4*>(&b1[c0]);
  ushort4 ov;
  ov.x = f2bf(elu1(acc.x * wi + bv.x));
  ov.y = f2bf(elu1(acc.y * wi + bv.y));
  ov.z = f2bf(elu1(acc.z * wi + bv.z));
  ov.w = f2bf(elu1(acc.w * wi + bv.w));
  reinterpret_cast<ushort4*>(hmidb + (size_t)v * 256)[lane] = ov;
}

// ---- GEMM2 + fused alpha2: h2b[N,64](bf16) = hmidb @ W2 ; as2/ad2[N] ----
__global__ __launch_bounds__(256) void gemm2_kernel(
    const unsigned short* __restrict__ A, const float* __restrict__ W,
    const float* __restrict__ att_s, const float* __restrict__ att_d,
    unsigned short* __restrict__ h2b, float* __restrict__ as2, float* __restrict__ ad2, int N) {
  __shared__ float as_[32][256];
  const int t = threadIdx.x;
  const int row0 = blockIdx.x * 32;
  const int rows = min(32, N - row0);
  {
    const uint4* ag = reinterpret_cast<const uint4*>(A + (size_t)row0 * 256);
    const int maxu4 = rows * 32;
    for (int i = t; i < 32 * 32; i += 256) {
      uint4 u = (i < maxu4) ? ag[i] : make_uint4(0u, 0u, 0u, 0u);
      float* dp = &as_[i >> 5][(i & 31) * 8];
      dp[0] = bf2f(u.x & 0xffffu); dp[1] = bf2f(u.x >> 16);
      dp[2] = bf2f(u.y & 0xffffu); dp[3] = bf2f(u.y >> 16);
      dp[4] = bf2f(u.z & 0xffffu); dp[5] = bf2f(u.z >> 16);
      dp[6] = bf2f(u.w & 0xffffu); dp[7] = bf2f(u.w >> 16);
    }
  }
  __syncthreads();
  const int ct = t & 15;  // cols ct*4..+3
  const int rt = t >> 4;  // rows rt*2..+1
  float acc[2][4] = {{0.f,0.f,0.f,0.f},{0.f,0.f,0.f,0.f}};
  for (int k4 = 0; k4 < 64; ++k4) {
    const float4 xr0 = *reinterpret_cast<const float4*>(&as_[rt * 2][k4 * 4]);
    const float4 xr1 = *reinterpret_cast<const float4*>(&as_[rt * 2 + 1][k4 * 4]);
#pragma unroll
    for (int kk = 0; kk < 4; kk++) {
      const float4 w = *reinterpret_cast<const float4*>(&W[(size_t)(k4 * 4 + kk) * 64 + ct * 4]);
      const float a0 = reinterpret_cast<const float*>(&xr0)[kk];
      const float a1 = reinterpret_cast<const float*>(&xr1)[kk];
      acc[0][0] = fmaf(a0, w.x, acc[0][0]); acc[0][1] = fmaf(a0, w.y, acc[0][1]);
      acc[0][2] = fmaf(a0, w.z, acc[0][2]); acc[0][3] = fmaf(a0, w.w, acc[0][3]);
      acc[1][0] = fmaf(a1, w.x, acc[1][0]); acc[1][1] = fmaf(a1, w.y, acc[1][1]);
      acc[1][2] = fmaf(a1, w.z, acc[1][2]); acc[1][3] = fmaf(a1, w.w, acc[1][3]);
    }
  }
  const float4 avs = *reinterpret_cast<const float4*>(&att_s[ct * 4]);
  const float4 avd = *reinterpret_cast<const float4*>(&att_d[ct * 4]);
  float ps[2], pd[2];
#pragma unroll
  for (int r = 0; r < 2; r++) {
    ps[r] = acc[r][0]*avs.x + acc[r][1]*avs.y + acc[r][2]*avs.z + acc[r][3]*avs.w;
    pd[r] = acc[r][0]*avd.x + acc[r][1]*avd.y + acc[r][2]*avd.z + acc[r][3]*avd.w;
#pragma unroll
    for (int o = 8; o > 0; o >>= 1) {
      ps[r] += __shfl_xor(ps[r], o, 64);
      pd[r] += __shfl_xor(pd[r], o, 64);
    }
  }
  if (((t & 63) & 15) == 0) {
#pragma unroll
    for (int r = 0; r < 2; r++) {
      const int row = row0 + rt * 2 + r;
      if (row < N) { as2[row] = ps[r]; ad2[row] = pd[r]; }
    }
  }
#pragma unroll
  for (int r = 0; r < 2; r++) {
    const int row = row0 + rt * 2 + r;
    if (row < N) {
      ushort4 ov;
      ov.x = f2bf(acc[r][0]); ov.y = f2bf(acc[r][1]);
      ov.z = f2bf(acc[r][2]); ov.w = f2bf(acc[r][3]);
      reinterpret_cast<ushort4*>(h2b + (size_t)row * 64)[ct] = ov;
    }
  }
}

// ---- gather2: bf16, half-wave per edge, 4-edge chunks per half ----
__global__ __launch_bounds__(256) void gather2w_kernel(
    const unsigned short* __restrict__ h2b, const float* __restrict__ w2,
    const float* __restrict__ wself2, const float* __restrict__ winv2,
    const float* __restrict__ b2, const int* __restrict__ row_start,
    const int* __restrict__ csr_src, float* __restrict__ h2, int N) {
  const int lane = threadIdx.x & 63;
  const int v = blockIdx.x * 4 + (threadIdx.x >> 6);
  if (v >= N) return;
  const int half = lane >> 5;   // 0/1: which edge of the pair
  const int cl = lane & 31;     // channels 2cl, 2cl+1
  const int rs = row_start[v], re = row_start[v + 1];
  float ax = 0.f, ay = 0.f;
  if (half == 0) {
    const unsigned int u = reinterpret_cast<const unsigned int*>(h2b + (size_t)v * 64)[cl];
    const float ws = wself2[v];
    ax = ws * bf2f(u & 0xffffu);
    ay = ws * bf2f(u >> 16);
  }
  if (rs < re) {
    const int rl = re - 1;
    int k = rs + half;
    int s0 = csr_src[min(k, rl)];
    int s1 = csr_src[min(k + 2, rl)];
    int s2 = csr_src[min(k + 4, rl)];
    int s3 = csr_src[min(k + 6, rl)];
    float t0 = w2[min(k, rl)];
    float t1 = w2[min(k + 2, rl)];
    float t2 = w2[min(k + 4, rl)];
    float t3 = w2[min(k + 6, rl)];
    float y0 = (k     < re) ? t0 : 0.f;
    float y1 = (k + 2 < re) ? t1 : 0.f;
    float y2 = (k + 4 < re) ? t2 : 0.f;
    float y3 = (k + 6 < re) ? t3 : 0.f;
    while (k < re) {
      const int kn = k + 8;
      const unsigned int f0 = reinterpret_cast<const unsigned int*>(h2b + (size_t)s0 * 64)[cl];
      const unsigned int f1 = reinterpret_cast<const unsigned int*>(h2b + (size_t)s1 * 64)[cl];
      const unsigned int f2 = reinterpret_cast<const unsigned int*>(h2b + (size_t)s2 * 64)[cl];
      const unsigned int f3 = reinterpret_cast<const unsigned int*>(h2b + (size_t)s3 * 64)[cl];
      const int kc0 = min(kn, rl), kc1 = min(kn + 2, rl), kc2 = min(kn + 4, rl), kc3 = min(kn + 6, rl);
      const int n0 = csr_src[kc0];
      const int n1 = csr_src[kc1];
      const int n2 = csr_src[kc2];
      const int n3 = csr_src[kc3];
      const float u0 = w2[kc0];
      const float u1 = w2[kc1];
      const float u2 = w2[kc2];
      const float u3 = w2[kc3];
      ax = fmaf(y0, bf2f(f0 & 0xffffu), ax); ay = fmaf(y0, bf2f(f0 >> 16), ay);
      ax = fmaf(y1, bf2f(f1 & 0xffffu), ax); ay = fmaf(y1, bf2f(f1 >> 16), ay);
      ax = fmaf(y2, bf2f(f2 & 0xffffu), ax); ay = fmaf(y2, bf2f(f2 >> 16), ay);
      ax = fmaf(y3, bf2f(f3 & 0xffffu), ax); ay = fmaf(y3, bf2f(f3 >> 16), ay);
      s0 = n0; s1 = n1; s2 = n2; s3 = n3;
      y0 = (kn     < re) ? u0 : 0.f;
      y1 = (kn + 2 < re) ? u1 : 0.f;
      y2 = (kn + 4 < re) ? u2 : 0.f;
      y3 = (kn + 6 < re) ? u3 : 0.f;
      k = kn;
    }
  }
  ax += __shfl_xor(ax, 32, 64);
  ay += __shfl_xor(ay, 32, 64);
  if (half == 0) {
    const float wi = winv2[v];
    float2 o;
    o.x = elu1(ax * wi + b2[2 * cl]);
    o.y = elu1(ay * wi + b2[2 * cl + 1]);
    reinterpret_cast<float2*>(h2 + (size_t)v * 64)[cl] = o;
  }
}

// ---------------- mean-pool over sorted batch ----------------
__global__ __launch_bounds__(256) void pool_kernel(
    const float* __restrict__ h2, const int* __restrict__ batch,
    float* __restrict__ pooled, float* __restrict__ cntf, int N) {
  const int lane = threadIdx.x & 63;
  const int gw = blockIdx.x * 4 + (threadIdx.x >> 6);
  const int s = gw * 64;
  if (s >= N) return;
  const int e = min(s + 64, N);
  int cur = batch[s];
  float racc = 0.f;
  int rc = 0;
  for (int v = s; v < e; v++) {
    const int g = batch[v];
    if (g != cur) {
      atomicAdd(&pooled[(size_t)cur * 64 + lane], racc);
      if (lane == 0) atomicAdd(&cntf[cur], (float)rc);
      racc = 0.f; rc = 0; cur = g;
    }
    racc += h2[(size_t)v * 64 + lane];
    rc++;
  }
  atomicAdd(&pooled[(size_t)cur * 64 + lane], racc);
  if (lane == 0) atomicAdd(&cntf[cur], (float)rc);
}

// ---------------- classifier ----------------
__global__ __launch_bounds__(64) void final_kernel(
    const float* __restrict__ pooled, const float* __restrict__ cntf,
    const float* __restrict__ Wc, const float* __restrict__ bc, float* __restrict__ out) {
  const int g = threadIdx.x;
  float acc = 0.f;
  for (int c = 0; c < 64; c++) acc = fmaf(pooled[(size_t)g * 64 + c], Wc[c], acc);
  const float cnt = fmaxf(cntf[g], 1.0f);
  out[g] = acc / cnt + bc[0];
}

extern "C" void kernel_launch(void* const* d_in, const int* in_sizes, int n_in,
                              void* d_out, int out_size, void* d_ws, size_t ws_size,
                              hipStream_t stream) {
  const float* x     = (const float*)d_in[0];
  const int*   ei    = (const int*)d_in[1];
  const int*   batch = (const int*)d_in[2];
  const float* W1    = (const float*)d_in[3];
  const float* atts1 = (const float*)d_in[4];
  const float* attd1 = (const float*)d_in[5];
  const float* b1    = (const float*)d_in[6];
  const float* W2    = (const float*)d_in[7];
  const float* atts2 = (const float*)d_in[8];
  const float* attd2 = (const float*)d_in[9];
  const float* b2    = (const float*)d_in[10];
  const float* Wc    = (const float*)d_in[11];
  const float* bc    = (const float*)d_in[12];
  float* out = (float*)d_out;

  const int N = in_sizes[0] / IN_F;   // 50000
  const int E = in_sizes[1] / 2;      // 800000
  const int* src = ei;
  const int* dst = ei + E;
  const int NB = (N + 255) / 256;     // scan blocks

  char* ws = (char*)d_ws;
  size_t off = 0;
  auto take = [&](size_t bytes) -> void* {
    void* p = ws + off;
    off = (off + bytes + 255) & ~(size_t)255;
    return p;
  };
  unsigned short* h1b   = (unsigned short*)take((size_t)N * 256 * 2);
  unsigned short* hmidb = (unsigned short*)take((size_t)N * 256 * 2);
  unsigned short* h2b   = (unsigned short*)take((size_t)N * 64 * 2);
  unsigned short* wthi  = (unsigned short*)take((size_t)256 * 128 * 2);
  unsigned short* wtlo  = (unsigned short*)take((size_t)256 * 128 * 2);
  float* as1      = (float*)take((size_t)N * 4 * sizeof(float));
  float* ad1      = (float*)take((size_t)N * 4 * sizeof(float));
  float* as2      = (float*)take((size_t)N * sizeof(float));
  float* ad2      = (float*)take((size_t)N * sizeof(float));
  int*   cnt      = (int*)take((size_t)N * sizeof(int));
  int*   row_start= (int*)take((size_t)(N + 1) * sizeof(int));
  int*   cursor   = (int*)take((size_t)N * sizeof(int));
  int*   csr_src  = (int*)take((size_t)E * sizeof(int));
  int*   bsum     = (int*)take((size_t)NB * sizeof(int));
  int*   boff     = (int*)take((size_t)NB * sizeof(int));
  float* pooled   = (float*)take((size_t)GROUPS * 64 * sizeof(float));
  float* cntf     = (float*)take((size_t)GROUPS * sizeof(float));
  float* w1       = (float*)take((size_t)E * 4 * sizeof(float));
  float* wself1   = (float*)take((size_t)N * 4 * sizeof(float));
  float* winv1    = (float*)take((size_t)N * 4 * sizeof(float));
  float* h2       = (float*)take((size_t)N * 64 * sizeof(float));
  // conv2 edge buffers alias conv1's (dead after gather1w)
  float* w2     = w1;
  float* wself2 = wself1;
  float* winv2  = winv1;

  hipMemsetAsync(cnt, 0, (size_t)N * sizeof(int), stream);
  hipMemsetAsync(pooled, 0, (size_t)GROUPS * 64 * sizeof(float), stream);
  hipMemsetAsync(cntf, 0, (size_t)GROUPS * sizeof(float), stream);

  // conv1 linear (MFMA, hi/lo-split) + fused attention coefficients
  prep_w1_kernel<<<128, 256, 0, stream>>>(W1, wthi, wtlo);
  gemm1_mfma_kernel<<<(N + 63) / 64, 256, 0, stream>>>(x, wthi, wtlo, atts1, attd1, h1b, as1, ad1, N);

  // CSR by dst (multi-block scan)
  hist_kernel<<<(E + 255) / 256, 256, 0, stream>>>(dst, cnt, E);
  block_reduce_kernel<<<NB, 256, 0, stream>>>(cnt, bsum, N);
  bsum_scan_kernel<<<1, 256, 0, stream>>>(bsum, boff, NB);
  block_scan_kernel<<<NB, 256, 0, stream>>>(cnt, boff, row_start, cursor, N);
  scatter_kernel<<<(E + 255) / 256, 256, 0, stream>>>(src, dst, cursor, csr_src, E);

  // conv1: edge weights then pure gather
  edge_w1_kernel<<<(N + 7) / 8, 256, 0, stream>>>(as1, ad1, row_start, csr_src, w1, wself1, winv1, N);
  gather1w_kernel<<<(N + 3) / 4, 256, 0, stream>>>(h1b, w1, wself1, winv1, b1, row_start, csr_src, hmidb, N);

  // conv2
  gemm2_kernel<<<(N + 31) / 32, 256, 0, stream>>>(hmidb, W2, atts2, attd2, h2b, as2, ad2, N);
  edge_w2_kernel<<<(N + 7) / 8, 256, 0, stream>>>(as2, ad2, row_start, csr_src, w2, wself2, winv2, N);
  gather2w_kernel<<<(N + 3) / 4, 256, 0, stream>>>(h2b, w2, wself2, winv2, b2, row_start, csr_src, h2, N);

  // pooling + classifier
  pool_kernel<<<((N + 63) / 64 + 3) / 4, 256, 0, stream>>>(h2, batch, pooled, cntf, N);
  final_kernel<<<1, 64, 0, stream>>>(pooled, cntf, Wc, bc, out);

  (void)n_in; (void)out_size; (void)ws_size;
}

// Round 9
// 327.572 us; speedup vs baseline: 1.1330x; 1.1330x over previous
//
#include <hip/hip_runtime.h>
#include <hip/hip_bf16.h>

constexpr int HEADS  = 4;
constexpr int HID    = 64;
constexpr int IN_F   = 128;
constexpr int GROUPS = 64;
constexpr float NEG_SLOPE = 0.2f;
constexpr float EPS_SM    = 1e-16f;

typedef short bf16x8 __attribute__((ext_vector_type(8)));
typedef float f32x4  __attribute__((ext_vector_type(4)));

static __device__ __forceinline__ float lrelu(float x) { return x >= 0.f ? x : NEG_SLOPE * x; }
static __device__ __forceinline__ float elu1(float x)  { return x > 0.f ? x : expm1f(x); }

static __device__ __forceinline__ float bf2f(unsigned int u) {
  union { unsigned int i; float f; } x; x.i = u << 16; return x.f;
}
static __device__ __forceinline__ unsigned short f2bf(float f) {
  union { float f; unsigned int i; } x; x.f = f;
  unsigned int lsb = (x.i >> 16) & 1u;
  x.i += 0x7fffu + lsb;
  return (unsigned short)(x.i >> 16);
}

// ---- prep: W1T_hi/lo[256][128] (bf16) from W1[128][256] fp32 ----
__global__ __launch_bounds__(256) void prep_w1_kernel(
    const float* __restrict__ W1, unsigned short* __restrict__ WThi,
    unsigned short* __restrict__ WTlo) {
  const int k = blockIdx.x;            // 0..127
  const int n = threadIdx.x;           // 0..255
  const float w = W1[(size_t)k * 256 + n];
  const unsigned short hi = f2bf(w);
  const float r = w - bf2f(hi);
  WThi[(size_t)n * 128 + k] = hi;
  WTlo[(size_t)n * 128 + k] = f2bf(r);
}

// ---- GEMM1 via MFMA, W-half staged in LDS (swizzled, conflict-free) ----
// 512 thr / 8 waves; block = 256 rows x 128 cols (col-half ch = blockIdx&1).
// Wave = 32 rows (2 row-groups sharing B frags). hi/lo split: 3 MFMAs / tile.
// Each 128-col half holds exactly 2 heads -> alpha epilogue block-local.
__global__ __launch_bounds__(512) void gemm1_mfma_kernel(
    const float* __restrict__ x,
    const unsigned short* __restrict__ WThi, const unsigned short* __restrict__ WTlo,
    const float* __restrict__ att_s, const float* __restrict__ att_d,
    unsigned short* __restrict__ h1b, float* __restrict__ as1, float* __restrict__ ad1, int N) {
  __shared__ unsigned short wl[2][128 * 128];   // [hi/lo][col][k], 16B-chunk swizzled
  const int tid = threadIdx.x;
  const int rowtile = blockIdx.x >> 1;
  const int ch = blockIdx.x & 1;                // column half (cols ch*128 .. +127)

  // stage W-half: 4096 x 16B chunks; swizzle chunk j -> j ^ (col&7)
#pragma unroll
  for (int it = 0; it < 8; ++it) {
    const int idx = it * 512 + tid;             // 0..4095
    const unsigned short* srcp = (it < 4) ? WThi : WTlo;
    const int arr = (it < 4) ? 0 : 1;
    const int rem = idx & 2047;
    const int c = rem >> 4;                     // local col 0..127
    const int j = rem & 15;                     // 16B chunk 0..15
    const uint4 v = *reinterpret_cast<const uint4*>(
        &srcp[((size_t)(ch * 128 + c)) * 128 + j * 8]);
    *reinterpret_cast<uint4*>(&wl[arr][c * 128 + ((j ^ (c & 7)) * 8)]) = v;
  }
  __syncthreads();

  const int lane = tid & 63;
  const int wid  = tid >> 6;                    // 0..7
  const int fr = lane & 15;
  const int fg = lane >> 4;
  const int wrow0 = rowtile * 256 + wid * 32;

  f32x4 acc[2][8];
#pragma unroll
  for (int rg = 0; rg < 2; rg++)
#pragma unroll
    for (int n = 0; n < 8; n++) acc[rg][n] = (f32x4){0.f, 0.f, 0.f, 0.f};

#pragma unroll
  for (int ks = 0; ks < 4; ks++) {
    bf16x8 ahi[2], alo[2];
#pragma unroll
    for (int rg = 0; rg < 2; rg++) {
      const int row = wrow0 + rg * 16 + fr;
      float xv[8];
      if (row < N) {
        const float4 a = *reinterpret_cast<const float4*>(&x[(size_t)row * IN_F + ks * 32 + fg * 8]);
        const float4 b = *reinterpret_cast<const float4*>(&x[(size_t)row * IN_F + ks * 32 + fg * 8 + 4]);
        xv[0]=a.x; xv[1]=a.y; xv[2]=a.z; xv[3]=a.w;
        xv[4]=b.x; xv[5]=b.y; xv[6]=b.z; xv[7]=b.w;
      } else {
#pragma unroll
        for (int j = 0; j < 8; j++) xv[j] = 0.f;
      }
#pragma unroll
      for (int j = 0; j < 8; j++) {
        const unsigned short h = f2bf(xv[j]);
        const float r = xv[j] - bf2f(h);
        ahi[rg][j] = (short)h;
        alo[rg][j] = (short)f2bf(r);
      }
    }
#pragma unroll
    for (int n = 0; n < 8; n++) {
      const int c = n * 16 + fr;
      const int slot = (((ks * 4 + fg) ^ (c & 7)) * 8);
      const bf16x8 bhi = *reinterpret_cast<const bf16x8*>(&wl[0][c * 128 + slot]);
      const bf16x8 blo = *reinterpret_cast<const bf16x8*>(&wl[1][c * 128 + slot]);
#pragma unroll
      for (int rg = 0; rg < 2; rg++) {
        acc[rg][n] = __builtin_amdgcn_mfma_f32_16x16x32_bf16(ahi[rg], bhi, acc[rg][n], 0, 0, 0);
        acc[rg][n] = __builtin_amdgcn_mfma_f32_16x16x32_bf16(alo[rg], bhi, acc[rg][n], 0, 0, 0);
        acc[rg][n] = __builtin_amdgcn_mfma_f32_16x16x32_bf16(ahi[rg], blo, acc[rg][n], 0, 0, 0);
      }
    }
  }

  // epilogue per row-group: fused alpha (2 local heads) + bf16 store
  const int colbase = ch * 128;
#pragma unroll
  for (int rg = 0; rg < 2; rg++) {
    float psS[2][4], psD[2][4];
#pragma unroll
    for (int h = 0; h < 2; h++)
#pragma unroll
      for (int r = 0; r < 4; r++) { psS[h][r] = 0.f; psD[h][r] = 0.f; }
#pragma unroll
    for (int n = 0; n < 8; n++) {
      const int col = colbase + n * 16 + fr;
      const float as_ = att_s[col];
      const float ad_ = att_d[col];
      const int h = n >> 2;
#pragma unroll
      for (int r = 0; r < 4; r++) {
        psS[h][r] = fmaf(acc[rg][n][r], as_, psS[h][r]);
        psD[h][r] = fmaf(acc[rg][n][r], ad_, psD[h][r]);
      }
    }
#pragma unroll
    for (int h = 0; h < 2; h++)
#pragma unroll
      for (int r = 0; r < 4; r++)
#pragma unroll
        for (int o = 8; o > 0; o >>= 1) {
          psS[h][r] += __shfl_xor(psS[h][r], o, 64);
          psD[h][r] += __shfl_xor(psD[h][r], o, 64);
        }
    if (fr == 0) {
#pragma unroll
      for (int r = 0; r < 4; r++) {
        const int row = wrow0 + rg * 16 + fg * 4 + r;
        if (row < N) {
#pragma unroll
          for (int h = 0; h < 2; h++) {
            as1[(size_t)row * 4 + ch * 2 + h] = psS[h][r];
            ad1[(size_t)row * 4 + ch * 2 + h] = psD[h][r];
          }
        }
      }
    }
#pragma unroll
    for (int r = 0; r < 4; r++) {
      const int row = wrow0 + rg * 16 + fg * 4 + r;
      if (row < N) {
#pragma unroll
        for (int n = 0; n < 8; n++)
          h1b[(size_t)row * 256 + colbase + n * 16 + fr] = f2bf(acc[rg][n][r]);
      }
    }
  }
}

// ---------------- CSR build ----------------
__global__ __launch_bounds__(256) void hist_kernel(const int* __restrict__ dst, int* __restrict__ cnt, int E) {
  const int e = blockIdx.x * 256 + threadIdx.x;
  if (e < E) atomicAdd(&cnt[dst[e]], 1);
}

__global__ __launch_bounds__(256) void block_reduce_kernel(
    const int* __restrict__ cnt, int* __restrict__ bsum, int N) {
  const int i = blockIdx.x * 256 + threadIdx.x;
  int v = (i < N) ? cnt[i] : 0;
#pragma unroll
  for (int o = 32; o > 0; o >>= 1) v += __shfl_xor(v, o, 64);
  __shared__ int ws_[4];
  if ((threadIdx.x & 63) == 0) ws_[threadIdx.x >> 6] = v;
  __syncthreads();
  if (threadIdx.x == 0)
    bsum[blockIdx.x] = ws_[0] + ws_[1] + ws_[2] + ws_[3];
}

__global__ __launch_bounds__(256) void bsum_scan_kernel(
    int* __restrict__ bsum, int* __restrict__ boff, int NB) {
  __shared__ int sdata[256];
  const int t = threadIdx.x;
  int v = (t < NB) ? bsum[t] : 0;
  sdata[t] = v;
  __syncthreads();
  for (int o = 1; o < 256; o <<= 1) {
    int x = (t >= o) ? sdata[t - o] : 0;
    __syncthreads();
    sdata[t] += x;
    __syncthreads();
  }
  if (t < NB) boff[t] = sdata[t] - v;   // exclusive
}

__global__ __launch_bounds__(256) void block_scan_kernel(
    const int* __restrict__ cnt, const int* __restrict__ boff,
    int* __restrict__ row_start, int* __restrict__ cursor, int N) {
  __shared__ int sdata[256];
  const int t = threadIdx.x;
  const int i = blockIdx.x * 256 + t;
  int v = (i < N) ? cnt[i] : 0;
  sdata[t] = v;
  __syncthreads();
  for (int o = 1; o < 256; o <<= 1) {
    int x = (t >= o) ? sdata[t - o] : 0;
    __syncthreads();
    sdata[t] += x;
    __syncthreads();
  }
  if (i < N) {
    const int rs = boff[blockIdx.x] + sdata[t] - v;
    row_start[i] = rs;
    cursor[i] = rs;
    if (i == N - 1) row_start[N] = rs + v;
  }
}

__global__ __launch_bounds__(256) void scatter_kernel(
    const int* __restrict__ src, const int* __restrict__ dst,
    int* __restrict__ cursor, int* __restrict__ csr_src, int E) {
  const int e = blockIdx.x * 256 + threadIdx.x;
  if (e < E) {
    const int d = dst[e];
    const int pos = atomicAdd(&cursor[d], 1);
    csr_src[pos] = src[e];
  }
}

// ---- edge weights conv1: one pass (scores bounded, max-shift unnecessary) ----
__global__ __launch_bounds__(256) void edge_w1_kernel(
    const float* __restrict__ as1, const float* __restrict__ ad1,
    const int* __restrict__ row_start, const int* __restrict__ csr_src,
    float* __restrict__ w1, float* __restrict__ wself, float* __restrict__ winv, int N) {
  const int sl = threadIdx.x & 31;
  const int v = blockIdx.x * 8 + (threadIdx.x >> 5);
  if (v >= N) return;
  const int rs = row_start[v], re = row_start[v + 1];
  const float4 adv = *reinterpret_cast<const float4*>(&ad1[(size_t)v * 4]);
  const float4 asv = *reinterpret_cast<const float4*>(&as1[(size_t)v * 4]);
  const float* adp = reinterpret_cast<const float*>(&adv);
  const float* asp = reinterpret_cast<const float*>(&asv);
  float den[HEADS] = {0.f, 0.f, 0.f, 0.f};
  for (int k = rs + sl; k < re; k += 32) {
    const int s = csr_src[k];
    const float4 av = *reinterpret_cast<const float4*>(&as1[(size_t)s * 4]);
    const float* ap = reinterpret_cast<const float*>(&av);
    float4 wv;
    float* wp = reinterpret_cast<float*>(&wv);
#pragma unroll
    for (int h = 0; h < HEADS; h++) {
      const float w = __expf(lrelu(ap[h] + adp[h]));
      wp[h] = w;
      den[h] += w;
    }
    *reinterpret_cast<float4*>(&w1[(size_t)k * 4]) = wv;
  }
#pragma unroll
  for (int h = 0; h < HEADS; h++)
#pragma unroll
    for (int o = 16; o > 0; o >>= 1) den[h] += __shfl_xor(den[h], o, 64);
  if (sl == 0) {
    float4 wsv, wiv;
    float* wsp = reinterpret_cast<float*>(&wsv);
    float* wip = reinterpret_cast<float*>(&wiv);
#pragma unroll
    for (int h = 0; h < HEADS; h++) {
      const float ws_ = __expf(lrelu(asp[h] + adp[h]));
      wsp[h] = ws_;
      wip[h] = 1.f / (den[h] + ws_ + EPS_SM);
    }
    *reinterpret_cast<float4*>(&wself[(size_t)v * 4]) = wsv;
    *reinterpret_cast<float4*>(&winv[(size_t)v * 4]) = wiv;
  }
}

// ---- edge weights conv2 (1 head): one pass ----
__global__ __launch_bounds__(256) void edge_w2_kernel(
    const float* __restrict__ as2, const float* __restrict__ ad2,
    const int* __restrict__ row_start, const int* __restrict__ csr_src,
    float* __restrict__ w2, float* __restrict__ wself2, float* __restrict__ winv2, int N) {
  const int sl = threadIdx.x & 31;
  const int v = blockIdx.x * 8 + (threadIdx.x >> 5);
  if (v >= N) return;
  const int rs = row_start[v], re = row_start[v + 1];
  const float adv = ad2[v];
  float den = 0.f;
  for (int k = rs + sl; k < re; k += 32) {
    const float w = __expf(lrelu(as2[csr_src[k]] + adv));
    w2[k] = w;
    den += w;
  }
#pragma unroll
  for (int o = 16; o > 0; o >>= 1) den += __shfl_xor(den, o, 64);
  if (sl == 0) {
    const float ws_ = __expf(lrelu(as2[v] + adv));
    wself2[v] = ws_;
    winv2[v] = 1.f / (den + ws_ + EPS_SM);
  }
}

// ---- gather1: bf16 gather, 4-edge chunks, one-chunk-ahead meta prefetch ----
__global__ __launch_bounds__(256) void gather1w_kernel(
    const unsigned short* __restrict__ h1b, const float* __restrict__ w1,
    const float* __restrict__ wself, const float* __restrict__ winv,
    const float* __restrict__ b1, const int* __restrict__ row_start,
    const int* __restrict__ csr_src, unsigned short* __restrict__ hmidb, int N) {
  const int lane = threadIdx.x & 63;
  const int v = blockIdx.x * 4 + (threadIdx.x >> 6);
  if (v >= N) return;
  const int hd = lane >> 4;       // head of this lane's 4 channels
  const int rs = row_start[v], re = row_start[v + 1];
  const float ws = wself[(size_t)v * 4 + hd];
  const ushort4 sv = reinterpret_cast<const ushort4*>(h1b + (size_t)v * 256)[lane];
  float4 acc;
  acc.x = ws * bf2f(sv.x); acc.y = ws * bf2f(sv.y);
  acc.z = ws * bf2f(sv.z); acc.w = ws * bf2f(sv.w);
  if (rs < re) {
    const int rl = re - 1;
    int k = rs;
    int s0 = csr_src[k];
    int s1 = csr_src[min(k + 1, rl)];
    int s2 = csr_src[min(k + 2, rl)];
    int s3 = csr_src[min(k + 3, rl)];
    float y0 = w1[(size_t)k * 4 + hd];
    float t1 = w1[(size_t)min(k + 1, rl) * 4 + hd];
    float t2 = w1[(size_t)min(k + 2, rl) * 4 + hd];
    float t3 = w1[(size_t)min(k + 3, rl) * 4 + hd];
    float y1 = (k + 1 < re) ? t1 : 0.f;
    float y2 = (k + 2 < re) ? t2 : 0.f;
    float y3 = (k + 3 < re) ? t3 : 0.f;
    while (k < re) {
      const int kn = k + 4;
      const ushort4 f0 = reinterpret_cast<const ushort4*>(h1b + (size_t)s0 * 256)[lane];
      const ushort4 f1 = reinterpret_cast<const ushort4*>(h1b + (size_t)s1 * 256)[lane];
      const ushort4 f2 = reinterpret_cast<const ushort4*>(h1b + (size_t)s2 * 256)[lane];
      const ushort4 f3 = reinterpret_cast<const ushort4*>(h1b + (size_t)s3 * 256)[lane];
      const int kc0 = min(kn, rl), kc1 = min(kn + 1, rl), kc2 = min(kn + 2, rl), kc3 = min(kn + 3, rl);
      const int n0 = csr_src[kc0];
      const int n1 = csr_src[kc1];
      const int n2 = csr_src[kc2];
      const int n3 = csr_src[kc3];
      const float u0 = w1[(size_t)kc0 * 4 + hd];
      const float u1 = w1[(size_t)kc1 * 4 + hd];
      const float u2 = w1[(size_t)kc2 * 4 + hd];
      const float u3 = w1[(size_t)kc3 * 4 + hd];
      acc.x = fmaf(y0, bf2f(f0.x), acc.x); acc.y = fmaf(y0, bf2f(f0.y), acc.y);
      acc.z = fmaf(y0, bf2f(f0.z), acc.z); acc.w = fmaf(y0, bf2f(f0.w), acc.w);
      acc.x = fmaf(y1, bf2f(f1.x), acc.x); acc.y = fmaf(y1, bf2f(f1.y), acc.y);
      acc.z = fmaf(y1, bf2f(f1.z), acc.z); acc.w = fmaf(y1, bf2f(f1.w), acc.w);
      acc.x = fmaf(y2, bf2f(f2.x), acc.x); acc.y = fmaf(y2, bf2f(f2.y), acc.y);
      acc.z = fmaf(y2, bf2f(f2.z), acc.z); acc.w = fmaf(y2, bf2f(f2.w), acc.w);
      acc.x = fmaf(y3, bf2f(f3.x), acc.x); acc.y = fmaf(y3, bf2f(f3.y), acc.y);
      acc.z = fmaf(y3, bf2f(f3.z), acc.z); acc.w = fmaf(y3, bf2f(f3.w), acc.w);
      s0 = n0; s1 = n1; s2 = n2; s3 = n3;
      y0 = (kn     < re) ? u0 : 0.f;
      y1 = (kn + 1 < re) ? u1 : 0.f;
      y2 = (kn + 2 < re) ? u2 : 0.f;
      y3 = (kn + 3 < re) ? u3 : 0.f;
      k = kn;
    }
  }
  const float wi = winv[(size_t)v * 4 + hd];
  const int c0 = lane * 4;
  const float4 bv = *reinterpret_cast<const float4*>(&b1[c0]);
  ushort4 ov;
  ov.x = f2bf(elu1(acc.x * wi + bv.x));
  ov.y = f2bf(elu1(acc.y * wi + bv.y));
  ov.z = f2bf(elu1(acc.z * wi + bv.z));
  ov.w = f2bf(elu1(acc.w * wi + bv.w));
  reinterpret_cast<ushort4*>(hmidb + (size_t)v * 256)[lane] = ov;
}

// ---- GEMM2 + fused alpha2: h2b[N,64](bf16) = hmidb @ W2 ; as2/ad2[N] ----
__global__ __launch_bounds__(256) void gemm2_kernel(
    const unsigned short* __restrict__ A, const float* __restrict__ W,
    const float* __restrict__ att_s, const float* __restrict__ att_d,
    unsigned short* __restrict__ h2b, float* __restrict__ as2, float* __restrict__ ad2, int N) {
  __shared__ float as_[32][256];
  const int t = threadIdx.x;
  const int row0 = blockIdx.x * 32;
  const int rows = min(32, N - row0);
  {
    const uint4* ag = reinterpret_cast<const uint4*>(A + (size_t)row0 * 256);
    const int maxu4 = rows * 32;
    for (int i = t; i < 32 * 32; i += 256) {
      uint4 u = (i < maxu4) ? ag[i] : make_uint4(0u, 0u, 0u, 0u);
      float* dp = &as_[i >> 5][(i & 31) * 8];
      dp[0] = bf2f(u.x & 0xffffu); dp[1] = bf2f(u.x >> 16);
      dp[2] = bf2f(u.y & 0xffffu); dp[3] = bf2f(u.y >> 16);
      dp[4] = bf2f(u.z & 0xffffu); dp[5] = bf2f(u.z >> 16);
      dp[6] = bf2f(u.w & 0xffffu); dp[7] = bf2f(u.w >> 16);
    }
  }
  __syncthreads();
  const int ct = t & 15;  // cols ct*4..+3
  const int rt = t >> 4;  // rows rt*2..+1
  float acc[2][4] = {{0.f,0.f,0.f,0.f},{0.f,0.f,0.f,0.f}};
  for (int k4 = 0; k4 < 64; ++k4) {
    const float4 xr0 = *reinterpret_cast<const float4*>(&as_[rt * 2][k4 * 4]);
    const float4 xr1 = *reinterpret_cast<const float4*>(&as_[rt * 2 + 1][k4 * 4]);
#pragma unroll
    for (int kk = 0; kk < 4; kk++) {
      const float4 w = *reinterpret_cast<const float4*>(&W[(size_t)(k4 * 4 + kk) * 64 + ct * 4]);
      const float a0 = reinterpret_cast<const float*>(&xr0)[kk];
      const float a1 = reinterpret_cast<const float*>(&xr1)[kk];
      acc[0][0] = fmaf(a0, w.x, acc[0][0]); acc[0][1] = fmaf(a0, w.y, acc[0][1]);
      acc[0][2] = fmaf(a0, w.z, acc[0][2]); acc[0][3] = fmaf(a0, w.w, acc[0][3]);
      acc[1][0] = fmaf(a1, w.x, acc[1][0]); acc[1][1] = fmaf(a1, w.y, acc[1][1]);
      acc[1][2] = fmaf(a1, w.z, acc[1][2]); acc[1][3] = fmaf(a1, w.w, acc[1][3]);
    }
  }
  const float4 avs = *reinterpret_cast<const float4*>(&att_s[ct * 4]);
  const float4 avd = *reinterpret_cast<const float4*>(&att_d[ct * 4]);
  float ps[2], pd[2];
#pragma unroll
  for (int r = 0; r < 2; r++) {
    ps[r] = acc[r][0]*avs.x + acc[r][1]*avs.y + acc[r][2]*avs.z + acc[r][3]*avs.w;
    pd[r] = acc[r][0]*avd.x + acc[r][1]*avd.y + acc[r][2]*avd.z + acc[r][3]*avd.w;
#pragma unroll
    for (int o = 8; o > 0; o >>= 1) {
      ps[r] += __shfl_xor(ps[r], o, 64);
      pd[r] += __shfl_xor(pd[r], o, 64);
    }
  }
  if (((t & 63) & 15) == 0) {
#pragma unroll
    for (int r = 0; r < 2; r++) {
      const int row = row0 + rt * 2 + r;
      if (row < N) { as2[row] = ps[r]; ad2[row] = pd[r]; }
    }
  }
#pragma unroll
  for (int r = 0; r < 2; r++) {
    const int row = row0 + rt * 2 + r;
    if (row < N) {
      ushort4 ov;
      ov.x = f2bf(acc[r][0]); ov.y = f2bf(acc[r][1]);
      ov.z = f2bf(acc[r][2]); ov.w = f2bf(acc[r][3]);
      reinterpret_cast<ushort4*>(h2b + (size_t)row * 64)[ct] = ov;
    }
  }
}

// ---- gather2: bf16, half-wave per edge, 4-edge chunks per half ----
__global__ __launch_bounds__(256) void gather2w_kernel(
    const unsigned short* __restrict__ h2b, const float* __restrict__ w2,
    const float* __restrict__ wself2, const float* __restrict__ winv2,
    const float* __restrict__ b2, const int* __restrict__ row_start,
    const int* __restrict__ csr_src, float* __restrict__ h2, int N) {
  const int lane = threadIdx.x & 63;
  const int v = blockIdx.x * 4 + (threadIdx.x >> 6);
  if (v >= N) return;
  const int half = lane >> 5;   // 0/1: which edge of the pair
  const int cl = lane & 31;     // channels 2cl, 2cl+1
  const int rs = row_start[v], re = row_start[v + 1];
  float ax = 0.f, ay = 0.f;
  if (half == 0) {
    const unsigned int u = reinterpret_cast<const unsigned int*>(h2b + (size_t)v * 64)[cl];
    const float ws = wself2[v];
    ax = ws * bf2f(u & 0xffffu);
    ay = ws * bf2f(u >> 16);
  }
  if (rs < re) {
    const int rl = re - 1;
    int k = rs + half;
    int s0 = csr_src[min(k, rl)];
    int s1 = csr_src[min(k + 2, rl)];
    int s2 = csr_src[min(k + 4, rl)];
    int s3 = csr_src[min(k + 6, rl)];
    float t0 = w2[min(k, rl)];
    float t1 = w2[min(k + 2, rl)];
    float t2 = w2[min(k + 4, rl)];
    float t3 = w2[min(k + 6, rl)];
    float y0 = (k     < re) ? t0 : 0.f;
    float y1 = (k + 2 < re) ? t1 : 0.f;
    float y2 = (k + 4 < re) ? t2 : 0.f;
    float y3 = (k + 6 < re) ? t3 : 0.f;
    while (k < re) {
      const int kn = k + 8;
      const unsigned int f0 = reinterpret_cast<const unsigned int*>(h2b + (size_t)s0 * 64)[cl];
      const unsigned int f1 = reinterpret_cast<const unsigned int*>(h2b + (size_t)s1 * 64)[cl];
      const unsigned int f2 = reinterpret_cast<const unsigned int*>(h2b + (size_t)s2 * 64)[cl];
      const unsigned int f3 = reinterpret_cast<const unsigned int*>(h2b + (size_t)s3 * 64)[cl];
      const int kc0 = min(kn, rl), kc1 = min(kn + 2, rl), kc2 = min(kn + 4, rl), kc3 = min(kn + 6, rl);
      const int n0 = csr_src[kc0];
      const int n1 = csr_src[kc1];
      const int n2 = csr_src[kc2];
      const int n3 = csr_src[kc3];
      const float u0 = w2[kc0];
      const float u1 = w2[kc1];
      const float u2 = w2[kc2];
      const float u3 = w2[kc3];
      ax = fmaf(y0, bf2f(f0 & 0xffffu), ax); ay = fmaf(y0, bf2f(f0 >> 16), ay);
      ax = fmaf(y1, bf2f(f1 & 0xffffu), ax); ay = fmaf(y1, bf2f(f1 >> 16), ay);
      ax = fmaf(y2, bf2f(f2 & 0xffffu), ax); ay = fmaf(y2, bf2f(f2 >> 16), ay);
      ax = fmaf(y3, bf2f(f3 & 0xffffu), ax); ay = fmaf(y3, bf2f(f3 >> 16), ay);
      s0 = n0; s1 = n1; s2 = n2; s3 = n3;
      y0 = (kn     < re) ? u0 : 0.f;
      y1 = (kn + 2 < re) ? u1 : 0.f;
      y2 = (kn + 4 < re) ? u2 : 0.f;
      y3 = (kn + 6 < re) ? u3 : 0.f;
      k = kn;
    }
  }
  ax += __shfl_xor(ax, 32, 64);
  ay += __shfl_xor(ay, 32, 64);
  if (half == 0) {
    const float wi = winv2[v];
    float2 o;
    o.x = elu1(ax * wi + b2[2 * cl]);
    o.y = elu1(ay * wi + b2[2 * cl + 1]);
    reinterpret_cast<float2*>(h2 + (size_t)v * 64)[cl] = o;
  }
}

// ---------------- mean-pool over sorted batch ----------------
__global__ __launch_bounds__(256) void pool_kernel(
    const float* __restrict__ h2, const int* __restrict__ batch,
    float* __restrict__ pooled, float* __restrict__ cntf, int N) {
  const int lane = threadIdx.x & 63;
  const int gw = blockIdx.x * 4 + (threadIdx.x >> 6);
  const int s = gw * 64;
  if (s >= N) return;
  const int e = min(s + 64, N);
  int cur = batch[s];
  float racc = 0.f;
  int rc = 0;
  for (int v = s; v < e; v++) {
    const int g = batch[v];
    if (g != cur) {
      atomicAdd(&pooled[(size_t)cur * 64 + lane], racc);
      if (lane == 0) atomicAdd(&cntf[cur], (float)rc);
      racc = 0.f; rc = 0; cur = g;
    }
    racc += h2[(size_t)v * 64 + lane];
    rc++;
  }
  atomicAdd(&pooled[(size_t)cur * 64 + lane], racc);
  if (lane == 0) atomicAdd(&cntf[cur], (float)rc);
}

// ---------------- classifier ----------------
__global__ __launch_bounds__(64) void final_kernel(
    const float* __restrict__ pooled, const float* __restrict__ cntf,
    const float* __restrict__ Wc, const float* __restrict__ bc, float* __restrict__ out) {
  const int g = threadIdx.x;
  float acc = 0.f;
  for (int c = 0; c < 64; c++) acc = fmaf(pooled[(size_t)g * 64 + c], Wc[c], acc);
  const float cnt = fmaxf(cntf[g], 1.0f);
  out[g] = acc / cnt + bc[0];
}

extern "C" void kernel_launch(void* const* d_in, const int* in_sizes, int n_in,
                              void* d_out, int out_size, void* d_ws, size_t ws_size,
                              hipStream_t stream) {
  const float* x     = (const float*)d_in[0];
  const int*   ei    = (const int*)d_in[1];
  const int*   batch = (const int*)d_in[2];
  const float* W1    = (const float*)d_in[3];
  const float* atts1 = (const float*)d_in[4];
  const float* attd1 = (const float*)d_in[5];
  const float* b1    = (const float*)d_in[6];
  const float* W2    = (const float*)d_in[7];
  const float* atts2 = (const float*)d_in[8];
  const float* attd2 = (const float*)d_in[9];
  const float* b2    = (const float*)d_in[10];
  const float* Wc    = (const float*)d_in[11];
  const float* bc    = (const float*)d_in[12];
  float* out = (float*)d_out;

  const int N = in_sizes[0] / IN_F;   // 50000
  const int E = in_sizes[1] / 2;      // 800000
  const int* src = ei;
  const int* dst = ei + E;
  const int NB = (N + 255) / 256;     // scan blocks
  const int NRT = (N + 255) / 256;    // gemm1 row tiles

  char* ws = (char*)d_ws;
  size_t off = 0;
  auto take = [&](size_t bytes) -> void* {
    void* p = ws + off;
    off = (off + bytes + 255) & ~(size_t)255;
    return p;
  };
  unsigned short* h1b   = (unsigned short*)take((size_t)N * 256 * 2);
  unsigned short* hmidb = (unsigned short*)take((size_t)N * 256 * 2);
  unsigned short* h2b   = (unsigned short*)take((size_t)N * 64 * 2);
  unsigned short* wthi  = (unsigned short*)take((size_t)256 * 128 * 2);
  unsigned short* wtlo  = (unsigned short*)take((size_t)256 * 128 * 2);
  float* as1      = (float*)take((size_t)N * 4 * sizeof(float));
  float* ad1      = (float*)take((size_t)N * 4 * sizeof(float));
  float* as2      = (float*)take((size_t)N * sizeof(float));
  float* ad2      = (float*)take((size_t)N * sizeof(float));
  int*   cnt      = (int*)take((size_t)N * sizeof(int));
  int*   row_start= (int*)take((size_t)(N + 1) * sizeof(int));
  int*   cursor   = (int*)take((size_t)N * sizeof(int));
  int*   csr_src  = (int*)take((size_t)E * sizeof(int));
  int*   bsum     = (int*)take((size_t)NB * sizeof(int));
  int*   boff     = (int*)take((size_t)NB * sizeof(int));
  float* pooled   = (float*)take((size_t)GROUPS * 64 * sizeof(float));
  float* cntf     = (float*)take((size_t)GROUPS * sizeof(float));
  float* w1       = (float*)take((size_t)E * 4 * sizeof(float));
  float* wself1   = (float*)take((size_t)N * 4 * sizeof(float));
  float* winv1    = (float*)take((size_t)N * 4 * sizeof(float));
  float* h2       = (float*)take((size_t)N * 64 * sizeof(float));
  // conv2 edge buffers alias conv1's (dead after gather1w)
  float* w2     = w1;
  float* wself2 = wself1;
  float* winv2  = winv1;

  hipMemsetAsync(cnt, 0, (size_t)N * sizeof(int), stream);
  hipMemsetAsync(pooled, 0, (size_t)GROUPS * 64 * sizeof(float), stream);
  hipMemsetAsync(cntf, 0, (size_t)GROUPS * sizeof(float), stream);

  // conv1 linear (MFMA, W in LDS, hi/lo-split) + fused attention coefficients
  prep_w1_kernel<<<128, 256, 0, stream>>>(W1, wthi, wtlo);
  gemm1_mfma_kernel<<<NRT * 2, 512, 0, stream>>>(x, wthi, wtlo, atts1, attd1, h1b, as1, ad1, N);

  // CSR by dst (multi-block scan)
  hist_kernel<<<(E + 255) / 256, 256, 0, stream>>>(dst, cnt, E);
  block_reduce_kernel<<<NB, 256, 0, stream>>>(cnt, bsum, N);
  bsum_scan_kernel<<<1, 256, 0, stream>>>(bsum, boff, NB);
  block_scan_kernel<<<NB, 256, 0, stream>>>(cnt, boff, row_start, cursor, N);
  scatter_kernel<<<(E + 255) / 256, 256, 0, stream>>>(src, dst, cursor, csr_src, E);

  // conv1: edge weights then pure gather
  edge_w1_kernel<<<(N + 7) / 8, 256, 0, stream>>>(as1, ad1, row_start, csr_src, w1, wself1, winv1, N);
  gather1w_kernel<<<(N + 3) / 4, 256, 0, stream>>>(h1b, w1, wself1, winv1, b1, row_start, csr_src, hmidb, N);

  // conv2
  gemm2_kernel<<<(N + 31) / 32, 256, 0, stream>>>(hmidb, W2, atts2, attd2, h2b, as2, ad2, N);
  edge_w2_kernel<<<(N + 7) / 8, 256, 0, stream>>>(as2, ad2, row_start, csr_src, w2, wself2, winv2, N);
  gather2w_kernel<<<(N + 3) / 4, 256, 0, stream>>>(h2b, w2, wself2, winv2, b2, row_start, csr_src, h2, N);

  // pooling + classifier
  pool_kernel<<<((N + 63) / 64 + 3) / 4, 256, 0, stream>>>(h2, batch, pooled, cntf, N);
  final_kernel<<<1, 64, 0, stream>>>(pooled, cntf, Wc, bc, out);

  (void)n_in; (void)out_size; (void)ws_size;
}

// Round 10
// 309.493 us; speedup vs baseline: 1.1992x; 1.0584x over previous
//
#include <hip/hip_runtime.h>
#include <hip/hip_bf16.h>

constexpr int HEADS  = 4;
constexpr int HID    = 64;
constexpr int IN_F   = 128;
constexpr int GROUPS = 64;
constexpr float NEG_SLOPE = 0.2f;
constexpr float EPS_SM    = 1e-16f;

typedef short bf16x8 __attribute__((ext_vector_type(8)));
typedef float f32x4  __attribute__((ext_vector_type(4)));

static __device__ __forceinline__ float lrelu(float x) { return x >= 0.f ? x : NEG_SLOPE * x; }
static __device__ __forceinline__ float elu1(float x)  { return x > 0.f ? x : expm1f(x); }

static __device__ __forceinline__ float bf2f(unsigned int u) {
  union { unsigned int i; float f; } x; x.i = u << 16; return x.f;
}
static __device__ __forceinline__ unsigned short f2bf(float f) {
  union { float f; unsigned int i; } x; x.f = f;
  unsigned int lsb = (x.i >> 16) & 1u;
  x.i += 0x7fffu + lsb;
  return (unsigned short)(x.i >> 16);
}
static __device__ __forceinline__ float sel4(float4 v, int i) {
  return i == 0 ? v.x : (i == 1 ? v.y : (i == 2 ? v.z : v.w));
}

// ---- prep: W1T_hi/lo[256][128] (bf16) from W1[128][256] fp32 ----
__global__ __launch_bounds__(256) void prep_w1_kernel(
    const float* __restrict__ W1, unsigned short* __restrict__ WThi,
    unsigned short* __restrict__ WTlo) {
  const int k = blockIdx.x;            // 0..127
  const int n = threadIdx.x;           // 0..255
  const float w = W1[(size_t)k * 256 + n];
  const unsigned short hi = f2bf(w);
  const float r = w - bf2f(hi);
  WThi[(size_t)n * 128 + k] = hi;
  WTlo[(size_t)n * 128 + k] = f2bf(r);
}

// ---- GEMM1 via MFMA, W-half staged in LDS (swizzled, conflict-free) ----
__global__ __launch_bounds__(512) void gemm1_mfma_kernel(
    const float* __restrict__ x,
    const unsigned short* __restrict__ WThi, const unsigned short* __restrict__ WTlo,
    const float* __restrict__ att_s, const float* __restrict__ att_d,
    unsigned short* __restrict__ h1b, float* __restrict__ as1, float* __restrict__ ad1, int N) {
  __shared__ unsigned short wl[2][128 * 128];   // [hi/lo][col][k], 16B-chunk swizzled
  const int tid = threadIdx.x;
  const int rowtile = blockIdx.x >> 1;
  const int ch = blockIdx.x & 1;                // column half (cols ch*128 .. +127)

#pragma unroll
  for (int it = 0; it < 8; ++it) {
    const int idx = it * 512 + tid;             // 0..4095
    const unsigned short* srcp = (it < 4) ? WThi : WTlo;
    const int arr = (it < 4) ? 0 : 1;
    const int rem = idx & 2047;
    const int c = rem >> 4;                     // local col 0..127
    const int j = rem & 15;                     // 16B chunk 0..15
    const uint4 v = *reinterpret_cast<const uint4*>(
        &srcp[((size_t)(ch * 128 + c)) * 128 + j * 8]);
    *reinterpret_cast<uint4*>(&wl[arr][c * 128 + ((j ^ (c & 7)) * 8)]) = v;
  }
  __syncthreads();

  const int lane = tid & 63;
  const int wid  = tid >> 6;                    // 0..7
  const int fr = lane & 15;
  const int fg = lane >> 4;
  const int wrow0 = rowtile * 256 + wid * 32;

  f32x4 acc[2][8];
#pragma unroll
  for (int rg = 0; rg < 2; rg++)
#pragma unroll
    for (int n = 0; n < 8; n++) acc[rg][n] = (f32x4){0.f, 0.f, 0.f, 0.f};

#pragma unroll
  for (int ks = 0; ks < 4; ks++) {
    bf16x8 ahi[2], alo[2];
#pragma unroll
    for (int rg = 0; rg < 2; rg++) {
      const int row = wrow0 + rg * 16 + fr;
      float xv[8];
      if (row < N) {
        const float4 a = *reinterpret_cast<const float4*>(&x[(size_t)row * IN_F + ks * 32 + fg * 8]);
        const float4 b = *reinterpret_cast<const float4*>(&x[(size_t)row * IN_F + ks * 32 + fg * 8 + 4]);
        xv[0]=a.x; xv[1]=a.y; xv[2]=a.z; xv[3]=a.w;
        xv[4]=b.x; xv[5]=b.y; xv[6]=b.z; xv[7]=b.w;
      } else {
#pragma unroll
        for (int j = 0; j < 8; j++) xv[j] = 0.f;
      }
#pragma unroll
      for (int j = 0; j < 8; j++) {
        const unsigned short h = f2bf(xv[j]);
        const float r = xv[j] - bf2f(h);
        ahi[rg][j] = (short)h;
        alo[rg][j] = (short)f2bf(r);
      }
    }
#pragma unroll
    for (int n = 0; n < 8; n++) {
      const int c = n * 16 + fr;
      const int slot = (((ks * 4 + fg) ^ (c & 7)) * 8);
      const bf16x8 bhi = *reinterpret_cast<const bf16x8*>(&wl[0][c * 128 + slot]);
      const bf16x8 blo = *reinterpret_cast<const bf16x8*>(&wl[1][c * 128 + slot]);
#pragma unroll
      for (int rg = 0; rg < 2; rg++) {
        acc[rg][n] = __builtin_amdgcn_mfma_f32_16x16x32_bf16(ahi[rg], bhi, acc[rg][n], 0, 0, 0);
        acc[rg][n] = __builtin_amdgcn_mfma_f32_16x16x32_bf16(alo[rg], bhi, acc[rg][n], 0, 0, 0);
        acc[rg][n] = __builtin_amdgcn_mfma_f32_16x16x32_bf16(ahi[rg], blo, acc[rg][n], 0, 0, 0);
      }
    }
  }

  const int colbase = ch * 128;
#pragma unroll
  for (int rg = 0; rg < 2; rg++) {
    float psS[2][4], psD[2][4];
#pragma unroll
    for (int h = 0; h < 2; h++)
#pragma unroll
      for (int r = 0; r < 4; r++) { psS[h][r] = 0.f; psD[h][r] = 0.f; }
#pragma unroll
    for (int n = 0; n < 8; n++) {
      const int col = colbase + n * 16 + fr;
      const float as_ = att_s[col];
      const float ad_ = att_d[col];
      const int h = n >> 2;
#pragma unroll
      for (int r = 0; r < 4; r++) {
        psS[h][r] = fmaf(acc[rg][n][r], as_, psS[h][r]);
        psD[h][r] = fmaf(acc[rg][n][r], ad_, psD[h][r]);
      }
    }
#pragma unroll
    for (int h = 0; h < 2; h++)
#pragma unroll
      for (int r = 0; r < 4; r++)
#pragma unroll
        for (int o = 8; o > 0; o >>= 1) {
          psS[h][r] += __shfl_xor(psS[h][r], o, 64);
          psD[h][r] += __shfl_xor(psD[h][r], o, 64);
        }
    if (fr == 0) {
#pragma unroll
      for (int r = 0; r < 4; r++) {
        const int row = wrow0 + rg * 16 + fg * 4 + r;
        if (row < N) {
#pragma unroll
          for (int h = 0; h < 2; h++) {
            as1[(size_t)row * 4 + ch * 2 + h] = psS[h][r];
            ad1[(size_t)row * 4 + ch * 2 + h] = psD[h][r];
          }
        }
      }
    }
#pragma unroll
    for (int r = 0; r < 4; r++) {
      const int row = wrow0 + rg * 16 + fg * 4 + r;
      if (row < N) {
#pragma unroll
        for (int n = 0; n < 8; n++)
          h1b[(size_t)row * 256 + colbase + n * 16 + fr] = f2bf(acc[rg][n][r]);
      }
    }
  }
}

// ---------------- CSR build ----------------
__global__ __launch_bounds__(256) void hist_kernel(const int* __restrict__ dst, int* __restrict__ cnt, int E) {
  const int e = blockIdx.x * 256 + threadIdx.x;
  if (e < E) atomicAdd(&cnt[dst[e]], 1);
}

__global__ __launch_bounds__(256) void block_reduce_kernel(
    const int* __restrict__ cnt, int* __restrict__ bsum, int N) {
  const int i = blockIdx.x * 256 + threadIdx.x;
  int v = (i < N) ? cnt[i] : 0;
#pragma unroll
  for (int o = 32; o > 0; o >>= 1) v += __shfl_xor(v, o, 64);
  __shared__ int ws_[4];
  if ((threadIdx.x & 63) == 0) ws_[threadIdx.x >> 6] = v;
  __syncthreads();
  if (threadIdx.x == 0)
    bsum[blockIdx.x] = ws_[0] + ws_[1] + ws_[2] + ws_[3];
}

__global__ __launch_bounds__(256) void bsum_scan_kernel(
    int* __restrict__ bsum, int* __restrict__ boff, int NB) {
  __shared__ int sdata[256];
  const int t = threadIdx.x;
  int v = (t < NB) ? bsum[t] : 0;
  sdata[t] = v;
  __syncthreads();
  for (int o = 1; o < 256; o <<= 1) {
    int x = (t >= o) ? sdata[t - o] : 0;
    __syncthreads();
    sdata[t] += x;
    __syncthreads();
  }
  if (t < NB) boff[t] = sdata[t] - v;   // exclusive
}

__global__ __launch_bounds__(256) void block_scan_kernel(
    const int* __restrict__ cnt, const int* __restrict__ boff,
    int* __restrict__ row_start, int* __restrict__ cursor, int N) {
  __shared__ int sdata[256];
  const int t = threadIdx.x;
  const int i = blockIdx.x * 256 + t;
  int v = (i < N) ? cnt[i] : 0;
  sdata[t] = v;
  __syncthreads();
  for (int o = 1; o < 256; o <<= 1) {
    int x = (t >= o) ? sdata[t - o] : 0;
    __syncthreads();
    sdata[t] += x;
    __syncthreads();
  }
  if (i < N) {
    const int rs = boff[blockIdx.x] + sdata[t] - v;
    row_start[i] = rs;
    cursor[i] = rs;
    if (i == N - 1) row_start[N] = rs + v;
  }
}

__global__ __launch_bounds__(256) void scatter_kernel(
    const int* __restrict__ src, const int* __restrict__ dst,
    int* __restrict__ cursor, int* __restrict__ csr_src, int E) {
  const int e = blockIdx.x * 256 + threadIdx.x;
  if (e < E) {
    const int d = dst[e];
    const int pos = atomicAdd(&cursor[d], 1);
    csr_src[pos] = src[e];
  }
}

// ---- gather1 FUSED: per-chunk lane-parallel weights -> wave LDS stash -> MLP=4 gather ----
__global__ __launch_bounds__(256) void gather1f_kernel(
    const unsigned short* __restrict__ h1b,
    const float* __restrict__ as1, const float* __restrict__ ad1,
    const float* __restrict__ b1, const int* __restrict__ row_start,
    const int* __restrict__ csr_src, unsigned short* __restrict__ hmidb, int N) {
  __shared__ float wbuf[4][256];    // [wave][edge*4 + head]
  __shared__ int   sbuf[4][64];     // [wave][edge]
  const int lane = threadIdx.x & 63;
  const int wv   = threadIdx.x >> 6;
  const int v = blockIdx.x * 4 + wv;
  if (v >= N) return;
  const int hd = lane >> 4;         // head of this lane's 4 channels
  const int rs = row_start[v], re = row_start[v + 1];
  const float4 adv = *reinterpret_cast<const float4*>(&ad1[(size_t)v * 4]);
  const float4 asv = *reinterpret_cast<const float4*>(&as1[(size_t)v * 4]);
  // self weight for my head only (runtime-index via selects, no scratch)
  const float wself_hd = __expf(lrelu(sel4(asv, hd) + sel4(adv, hd)));
  const ushort4 sv = reinterpret_cast<const ushort4*>(h1b + (size_t)v * 256)[lane];
  float4 acc;
  acc.x = wself_hd * bf2f(sv.x); acc.y = wself_hd * bf2f(sv.y);
  acc.z = wself_hd * bf2f(sv.z); acc.w = wself_hd * bf2f(sv.w);
  float4 denp = make_float4(0.f, 0.f, 0.f, 0.f);
  const float* adp = reinterpret_cast<const float*>(&adv);

  for (int base = rs; base < re; base += 64) {
    const int cnt = min(64, re - base);
    int s = v;
    float4 w4 = make_float4(0.f, 0.f, 0.f, 0.f);
    if (lane < cnt) {
      s = csr_src[base + lane];
      const float4 av = *reinterpret_cast<const float4*>(&as1[(size_t)s * 4]);
      const float* ap = reinterpret_cast<const float*>(&av);
      float* wp = reinterpret_cast<float*>(&w4);
#pragma unroll
      for (int h = 0; h < HEADS; h++) wp[h] = __expf(lrelu(ap[h] + adp[h]));
      denp.x += w4.x; denp.y += w4.y; denp.z += w4.z; denp.w += w4.w;
    }
    sbuf[wv][lane] = s;
    *reinterpret_cast<float4*>(&wbuf[wv][lane * 4]) = w4;
    // same-wave LDS write->read: lgkmcnt ordering, no cross-wave race
    const int cntp = (cnt + 3) & ~3;
    for (int j = 0; j < cntp; j += 4) {
      const int s0 = sbuf[wv][j],     s1 = sbuf[wv][j + 1];
      const int s2 = sbuf[wv][j + 2], s3 = sbuf[wv][j + 3];
      const float y0 = wbuf[wv][(j) * 4 + hd];
      const float y1 = wbuf[wv][(j + 1) * 4 + hd];
      const float y2 = wbuf[wv][(j + 2) * 4 + hd];
      const float y3 = wbuf[wv][(j + 3) * 4 + hd];
      const ushort4 f0 = reinterpret_cast<const ushort4*>(h1b + (size_t)s0 * 256)[lane];
      const ushort4 f1 = reinterpret_cast<const ushort4*>(h1b + (size_t)s1 * 256)[lane];
      const ushort4 f2 = reinterpret_cast<const ushort4*>(h1b + (size_t)s2 * 256)[lane];
      const ushort4 f3 = reinterpret_cast<const ushort4*>(h1b + (size_t)s3 * 256)[lane];
      acc.x = fmaf(y0, bf2f(f0.x), acc.x); acc.y = fmaf(y0, bf2f(f0.y), acc.y);
      acc.z = fmaf(y0, bf2f(f0.z), acc.z); acc.w = fmaf(y0, bf2f(f0.w), acc.w);
      acc.x = fmaf(y1, bf2f(f1.x), acc.x); acc.y = fmaf(y1, bf2f(f1.y), acc.y);
      acc.z = fmaf(y1, bf2f(f1.z), acc.z); acc.w = fmaf(y1, bf2f(f1.w), acc.w);
      acc.x = fmaf(y2, bf2f(f2.x), acc.x); acc.y = fmaf(y2, bf2f(f2.y), acc.y);
      acc.z = fmaf(y2, bf2f(f2.z), acc.z); acc.w = fmaf(y2, bf2f(f2.w), acc.w);
      acc.x = fmaf(y3, bf2f(f3.x), acc.x); acc.y = fmaf(y3, bf2f(f3.y), acc.y);
      acc.z = fmaf(y3, bf2f(f3.z), acc.z); acc.w = fmaf(y3, bf2f(f3.w), acc.w);
    }
  }
  // reduce per-head denominators across lanes
#pragma unroll
  for (int o = 32; o > 0; o >>= 1) {
    denp.x += __shfl_xor(denp.x, o, 64);
    denp.y += __shfl_xor(denp.y, o, 64);
    denp.z += __shfl_xor(denp.z, o, 64);
    denp.w += __shfl_xor(denp.w, o, 64);
  }
  const float wi = 1.f / (sel4(denp, hd) + wself_hd + EPS_SM);
  const float4 bv = *reinterpret_cast<const float4*>(&b1[lane * 4]);
  ushort4 ov;
  ov.x = f2bf(elu1(acc.x * wi + bv.x));
  ov.y = f2bf(elu1(acc.y * wi + bv.y));
  ov.z = f2bf(elu1(acc.z * wi + bv.z));
  ov.w = f2bf(elu1(acc.w * wi + bv.w));
  reinterpret_cast<ushort4*>(hmidb + (size_t)v * 256)[lane] = ov;
}

// ---- GEMM2 + fused alpha2: h2b[N,64](bf16) = hmidb @ W2 ; as2/ad2[N] ----
__global__ __launch_bounds__(256) void gemm2_kernel(
    const unsigned short* __restrict__ A, const float* __restrict__ W,
    const float* __restrict__ att_s, const float* __restrict__ att_d,
    unsigned short* __restrict__ h2b, float* __restrict__ as2, float* __restrict__ ad2, int N) {
  __shared__ float as_[32][256];
  const int t = threadIdx.x;
  const int row0 = blockIdx.x * 32;
  const int rows = min(32, N - row0);
  {
    const uint4* ag = reinterpret_cast<const uint4*>(A + (size_t)row0 * 256);
    const int maxu4 = rows * 32;
    for (int i = t; i < 32 * 32; i += 256) {
      uint4 u = (i < maxu4) ? ag[i] : make_uint4(0u, 0u, 0u, 0u);
      float* dp = &as_[i >> 5][(i & 31) * 8];
      dp[0] = bf2f(u.x & 0xffffu); dp[1] = bf2f(u.x >> 16);
      dp[2] = bf2f(u.y & 0xffffu); dp[3] = bf2f(u.y >> 16);
      dp[4] = bf2f(u.z & 0xffffu); dp[5] = bf2f(u.z >> 16);
      dp[6] = bf2f(u.w & 0xffffu); dp[7] = bf2f(u.w >> 16);
    }
  }
  __syncthreads();
  const int ct = t & 15;  // cols ct*4..+3
  const int rt = t >> 4;  // rows rt*2..+1
  float acc[2][4] = {{0.f,0.f,0.f,0.f},{0.f,0.f,0.f,0.f}};
  for (int k4 = 0; k4 < 64; ++k4) {
    const float4 xr0 = *reinterpret_cast<const float4*>(&as_[rt * 2][k4 * 4]);
    const float4 xr1 = *reinterpret_cast<const float4*>(&as_[rt * 2 + 1][k4 * 4]);
#pragma unroll
    for (int kk = 0; kk < 4; kk++) {
      const float4 w = *reinterpret_cast<const float4*>(&W[(size_t)(k4 * 4 + kk) * 64 + ct * 4]);
      const float a0 = reinterpret_cast<const float*>(&xr0)[kk];
      const float a1 = reinterpret_cast<const float*>(&xr1)[kk];
      acc[0][0] = fmaf(a0, w.x, acc[0][0]); acc[0][1] = fmaf(a0, w.y, acc[0][1]);
      acc[0][2] = fmaf(a0, w.z, acc[0][2]); acc[0][3] = fmaf(a0, w.w, acc[0][3]);
      acc[1][0] = fmaf(a1, w.x, acc[1][0]); acc[1][1] = fmaf(a1, w.y, acc[1][1]);
      acc[1][2] = fmaf(a1, w.z, acc[1][2]); acc[1][3] = fmaf(a1, w.w, acc[1][3]);
    }
  }
  const float4 avs = *reinterpret_cast<const float4*>(&att_s[ct * 4]);
  const float4 avd = *reinterpret_cast<const float4*>(&att_d[ct * 4]);
  float ps[2], pd[2];
#pragma unroll
  for (int r = 0; r < 2; r++) {
    ps[r] = acc[r][0]*avs.x + acc[r][1]*avs.y + acc[r][2]*avs.z + acc[r][3]*avs.w;
    pd[r] = acc[r][0]*avd.x + acc[r][1]*avd.y + acc[r][2]*avd.z + acc[r][3]*avd.w;
#pragma unroll
    for (int o = 8; o > 0; o >>= 1) {
      ps[r] += __shfl_xor(ps[r], o, 64);
      pd[r] += __shfl_xor(pd[r], o, 64);
    }
  }
  if (((t & 63) & 15) == 0) {
#pragma unroll
    for (int r = 0; r < 2; r++) {
      const int row = row0 + rt * 2 + r;
      if (row < N) { as2[row] = ps[r]; ad2[row] = pd[r]; }
    }
  }
#pragma unroll
  for (int r = 0; r < 2; r++) {
    const int row = row0 + rt * 2 + r;
    if (row < N) {
      ushort4 ov;
      ov.x = f2bf(acc[r][0]); ov.y = f2bf(acc[r][1]);
      ov.z = f2bf(acc[r][2]); ov.w = f2bf(acc[r][3]);
      reinterpret_cast<ushort4*>(h2b + (size_t)row * 64)[ct] = ov;
    }
  }
}

// ---- gather2 FUSED: lane-parallel weights -> wave LDS stash -> half-wave MLP=4 gather ----
__global__ __launch_bounds__(256) void gather2f_kernel(
    const unsigned short* __restrict__ h2b,
    const float* __restrict__ as2, const float* __restrict__ ad2,
    const float* __restrict__ b2, const int* __restrict__ row_start,
    const int* __restrict__ csr_src, float* __restrict__ h2, int N) {
  __shared__ float wbuf[4][64];
  __shared__ int   sbuf[4][64];
  const int lane = threadIdx.x & 63;
  const int wv   = threadIdx.x >> 6;
  const int v = blockIdx.x * 4 + wv;
  if (v >= N) return;
  const int half = lane >> 5;   // which edge-parity this half handles
  const int cl = lane & 31;     // channels 2cl, 2cl+1
  const int rs = row_start[v], re = row_start[v + 1];
  const float adv = ad2[v];
  const float wself = __expf(lrelu(as2[v] + adv));
  float ax = 0.f, ay = 0.f;
  if (half == 0) {
    const unsigned int u = reinterpret_cast<const unsigned int*>(h2b + (size_t)v * 64)[cl];
    ax = wself * bf2f(u & 0xffffu);
    ay = wself * bf2f(u >> 16);
  }
  float denp = 0.f;
  for (int base = rs; base < re; base += 64) {
    const int cnt = min(64, re - base);
    int s = v;
    float w = 0.f;
    if (lane < cnt) {
      s = csr_src[base + lane];
      w = __expf(lrelu(as2[s] + adv));
      denp += w;
    }
    sbuf[wv][lane] = s;
    wbuf[wv][lane] = w;
    const int cntp = (cnt + 7) & ~7;
    for (int j = 0; j < cntp; j += 8) {
      const int b0 = j + half;
      const int s0 = sbuf[wv][b0],     s1 = sbuf[wv][b0 + 2];
      const int s2 = sbuf[wv][b0 + 4], s3 = sbuf[wv][b0 + 6];
      const float y0 = wbuf[wv][b0],     y1 = wbuf[wv][b0 + 2];
      const float y2 = wbuf[wv][b0 + 4], y3 = wbuf[wv][b0 + 6];
      const unsigned int f0 = reinterpret_cast<const unsigned int*>(h2b + (size_t)s0 * 64)[cl];
      const unsigned int f1 = reinterpret_cast<const unsigned int*>(h2b + (size_t)s1 * 64)[cl];
      const unsigned int f2 = reinterpret_cast<const unsigned int*>(h2b + (size_t)s2 * 64)[cl];
      const unsigned int f3 = reinterpret_cast<const unsigned int*>(h2b + (size_t)s3 * 64)[cl];
      ax = fmaf(y0, bf2f(f0 & 0xffffu), ax); ay = fmaf(y0, bf2f(f0 >> 16), ay);
      ax = fmaf(y1, bf2f(f1 & 0xffffu), ax); ay = fmaf(y1, bf2f(f1 >> 16), ay);
      ax = fmaf(y2, bf2f(f2 & 0xffffu), ax); ay = fmaf(y2, bf2f(f2 >> 16), ay);
      ax = fmaf(y3, bf2f(f3 & 0xffffu), ax); ay = fmaf(y3, bf2f(f3 >> 16), ay);
    }
  }
#pragma unroll
  for (int o = 32; o > 0; o >>= 1) denp += __shfl_xor(denp, o, 64);
  ax += __shfl_xor(ax, 32, 64);
  ay += __shfl_xor(ay, 32, 64);
  if (half == 0) {
    const float wi = 1.f / (denp + wself + EPS_SM);
    float2 o;
    o.x = elu1(ax * wi + b2[2 * cl]);
    o.y = elu1(ay * wi + b2[2 * cl + 1]);
    reinterpret_cast<float2*>(h2 + (size_t)v * 64)[cl] = o;
  }
}

// ---------------- mean-pool over sorted batch ----------------
__global__ __launch_bounds__(256) void pool_kernel(
    const float* __restrict__ h2, const int* __restrict__ batch,
    float* __restrict__ pooled, float* __restrict__ cntf, int N) {
  const int lane = threadIdx.x & 63;
  const int gw = blockIdx.x * 4 + (threadIdx.x >> 6);
  const int s = gw * 64;
  if (s >= N) return;
  const int e = min(s + 64, N);
  int cur = batch[s];
  float racc = 0.f;
  int rc = 0;
  for (int v = s; v < e; v++) {
    const int g = batch[v];
    if (g != cur) {
      atomicAdd(&pooled[(size_t)cur * 64 + lane], racc);
      if (lane == 0) atomicAdd(&cntf[cur], (float)rc);
      racc = 0.f; rc = 0; cur = g;
    }
    racc += h2[(size_t)v * 64 + lane];
    rc++;
  }
  atomicAdd(&pooled[(size_t)cur * 64 + lane], racc);
  if (lane == 0) atomicAdd(&cntf[cur], (float)rc);
}

// ---------------- classifier ----------------
__global__ __launch_bounds__(64) void final_kernel(
    const float* __restrict__ pooled, const float* __restrict__ cntf,
    const float* __restrict__ Wc, const float* __restrict__ bc, float* __restrict__ out) {
  const int g = threadIdx.x;
  float acc = 0.f;
  for (int c = 0; c < 64; c++) acc = fmaf(pooled[(size_t)g * 64 + c], Wc[c], acc);
  const float cnt = fmaxf(cntf[g], 1.0f);
  out[g] = acc / cnt + bc[0];
}

extern "C" void kernel_launch(void* const* d_in, const int* in_sizes, int n_in,
                              void* d_out, int out_size, void* d_ws, size_t ws_size,
                              hipStream_t stream) {
  const float* x     = (const float*)d_in[0];
  const int*   ei    = (const int*)d_in[1];
  const int*   batch = (const int*)d_in[2];
  const float* W1    = (const float*)d_in[3];
  const float* atts1 = (const float*)d_in[4];
  const float* attd1 = (const float*)d_in[5];
  const float* b1    = (const float*)d_in[6];
  const float* W2    = (const float*)d_in[7];
  const float* atts2 = (const float*)d_in[8];
  const float* attd2 = (const float*)d_in[9];
  const float* b2    = (const float*)d_in[10];
  const float* Wc    = (const float*)d_in[11];
  const float* bc    = (const float*)d_in[12];
  float* out = (float*)d_out;

  const int N = in_sizes[0] / IN_F;   // 50000
  const int E = in_sizes[1] / 2;      // 800000
  const int* src = ei;
  const int* dst = ei + E;
  const int NB = (N + 255) / 256;     // scan blocks
  const int NRT = (N + 255) / 256;    // gemm1 row tiles

  char* ws = (char*)d_ws;
  size_t off = 0;
  auto take = [&](size_t bytes) -> void* {
    void* p = ws + off;
    off = (off + bytes + 255) & ~(size_t)255;
    return p;
  };
  unsigned short* h1b   = (unsigned short*)take((size_t)N * 256 * 2);
  unsigned short* hmidb = (unsigned short*)take((size_t)N * 256 * 2);
  unsigned short* h2b   = (unsigned short*)take((size_t)N * 64 * 2);
  unsigned short* wthi  = (unsigned short*)take((size_t)256 * 128 * 2);
  unsigned short* wtlo  = (unsigned short*)take((size_t)256 * 128 * 2);
  float* as1      = (float*)take((size_t)N * 4 * sizeof(float));
  float* ad1      = (float*)take((size_t)N * 4 * sizeof(float));
  float* as2      = (float*)take((size_t)N * sizeof(float));
  float* ad2      = (float*)take((size_t)N * sizeof(float));
  int*   cnt      = (int*)take((size_t)N * sizeof(int));
  int*   row_start= (int*)take((size_t)(N + 1) * sizeof(int));
  int*   cursor   = (int*)take((size_t)N * sizeof(int));
  int*   csr_src  = (int*)take((size_t)E * sizeof(int));
  int*   bsum     = (int*)take((size_t)NB * sizeof(int));
  int*   boff     = (int*)take((size_t)NB * sizeof(int));
  float* pooled   = (float*)take((size_t)GROUPS * 64 * sizeof(float));
  float* cntf     = (float*)take((size_t)GROUPS * sizeof(float));
  float* h2       = (float*)take((size_t)N * 64 * sizeof(float));

  hipMemsetAsync(cnt, 0, (size_t)N * sizeof(int), stream);
  hipMemsetAsync(pooled, 0, (size_t)GROUPS * 64 * sizeof(float), stream);
  hipMemsetAsync(cntf, 0, (size_t)GROUPS * sizeof(float), stream);

  // conv1 linear (MFMA, W in LDS, hi/lo-split) + fused attention coefficients
  prep_w1_kernel<<<128, 256, 0, stream>>>(W1, wthi, wtlo);
  gemm1_mfma_kernel<<<NRT * 2, 512, 0, stream>>>(x, wthi, wtlo, atts1, attd1, h1b, as1, ad1, N);

  // CSR by dst (multi-block scan)
  hist_kernel<<<(E + 255) / 256, 256, 0, stream>>>(dst, cnt, E);
  block_reduce_kernel<<<NB, 256, 0, stream>>>(cnt, bsum, N);
  bsum_scan_kernel<<<1, 256, 0, stream>>>(bsum, boff, NB);
  block_scan_kernel<<<NB, 256, 0, stream>>>(cnt, boff, row_start, cursor, N);
  scatter_kernel<<<(E + 255) / 256, 256, 0, stream>>>(src, dst, cursor, csr_src, E);

  // conv1 aggregate (weights fused in)
  gather1f_kernel<<<(N + 3) / 4, 256, 0, stream>>>(h1b, as1, ad1, b1, row_start, csr_src, hmidb, N);

  // conv2
  gemm2_kernel<<<(N + 31) / 32, 256, 0, stream>>>(hmidb, W2, atts2, attd2, h2b, as2, ad2, N);
  gather2f_kernel<<<(N + 3) / 4, 256, 0, stream>>>(h2b, as2, ad2, b2, row_start, csr_src, h2, N);

  // pooling + classifier
  pool_kernel<<<((N + 63) / 64 + 3) / 4, 256, 0, stream>>>(h2, batch, pooled, cntf, N);
  final_kernel<<<1, 64, 0, stream>>>(pooled, cntf, Wc, bc, out);

  (void)n_in; (void)out_size; (void)ws_size;
}

// Round 11
// 265.374 us; speedup vs baseline: 1.3986x; 1.1663x over previous
//
#include <hip/hip_runtime.h>
#include <hip/hip_bf16.h>

constexpr int HEADS  = 4;
constexpr int HID    = 64;
constexpr int IN_F   = 128;
constexpr int GROUPS = 64;
constexpr float NEG_SLOPE = 0.2f;
constexpr float EPS_SM    = 1e-16f;

typedef short bf16x8 __attribute__((ext_vector_type(8)));
typedef float f32x4  __attribute__((ext_vector_type(4)));

static __device__ __forceinline__ float lrelu(float x) { return x >= 0.f ? x : NEG_SLOPE * x; }
static __device__ __forceinline__ float elu1(float x)  { return x > 0.f ? x : expm1f(x); }

static __device__ __forceinline__ float bf2f(unsigned int u) {
  union { unsigned int i; float f; } x; x.i = u << 16; return x.f;
}
static __device__ __forceinline__ unsigned short f2bf(float f) {
  union { float f; unsigned int i; } x; x.f = f;
  unsigned int lsb = (x.i >> 16) & 1u;
  x.i += 0x7fffu + lsb;
  return (unsigned short)(x.i >> 16);
}
static __device__ __forceinline__ float sel4(float4 v, int i) {
  return i == 0 ? v.x : (i == 1 ? v.y : (i == 2 ? v.z : v.w));
}

// ---- prep: W1T_hi/lo[256][128] (bf16) from W1[128][256] fp32 ----
__global__ __launch_bounds__(256) void prep_w1_kernel(
    const float* __restrict__ W1, unsigned short* __restrict__ WThi,
    unsigned short* __restrict__ WTlo) {
  const int k = blockIdx.x;            // 0..127
  const int n = threadIdx.x;           // 0..255
  const float w = W1[(size_t)k * 256 + n];
  const unsigned short hi = f2bf(w);
  const float r = w - bf2f(hi);
  WThi[(size_t)n * 128 + k] = hi;
  WTlo[(size_t)n * 128 + k] = f2bf(r);
}

// ---- prep: W2T_hi/lo[64][256] (bf16) from W2[256][64] fp32 ----
__global__ __launch_bounds__(256) void prep_w2_kernel(
    const float* __restrict__ W2, unsigned short* __restrict__ WThi,
    unsigned short* __restrict__ WTlo) {
  const int k = threadIdx.x;           // 0..255
  const int n = blockIdx.x;            // 0..63
  const float w = W2[(size_t)k * 64 + n];
  const unsigned short hi = f2bf(w);
  WThi[(size_t)n * 256 + k] = hi;
  WTlo[(size_t)n * 256 + k] = f2bf(w - bf2f(hi));
}

// ---- GEMM1 via MFMA, W-half staged in LDS (swizzled, conflict-free) ----
__global__ __launch_bounds__(512) void gemm1_mfma_kernel(
    const float* __restrict__ x,
    const unsigned short* __restrict__ WThi, const unsigned short* __restrict__ WTlo,
    const float* __restrict__ att_s, const float* __restrict__ att_d,
    unsigned short* __restrict__ h1b, float* __restrict__ as1, float* __restrict__ ad1, int N) {
  __shared__ unsigned short wl[2][128 * 128];   // [hi/lo][col][k], 16B-chunk swizzled
  const int tid = threadIdx.x;
  const int rowtile = blockIdx.x >> 1;
  const int ch = blockIdx.x & 1;                // column half (cols ch*128 .. +127)

#pragma unroll
  for (int it = 0; it < 8; ++it) {
    const int idx = it * 512 + tid;             // 0..4095
    const unsigned short* srcp = (it < 4) ? WThi : WTlo;
    const int arr = (it < 4) ? 0 : 1;
    const int rem = idx & 2047;
    const int c = rem >> 4;                     // local col 0..127
    const int j = rem & 15;                     // 16B chunk 0..15
    const uint4 v = *reinterpret_cast<const uint4*>(
        &srcp[((size_t)(ch * 128 + c)) * 128 + j * 8]);
    *reinterpret_cast<uint4*>(&wl[arr][c * 128 + ((j ^ (c & 7)) * 8)]) = v;
  }
  __syncthreads();

  const int lane = tid & 63;
  const int wid  = tid >> 6;                    // 0..7
  const int fr = lane & 15;
  const int fg = lane >> 4;
  const int wrow0 = rowtile * 256 + wid * 32;

  f32x4 acc[2][8];
#pragma unroll
  for (int rg = 0; rg < 2; rg++)
#pragma unroll
    for (int n = 0; n < 8; n++) acc[rg][n] = (f32x4){0.f, 0.f, 0.f, 0.f};

#pragma unroll
  for (int ks = 0; ks < 4; ks++) {
    bf16x8 ahi[2], alo[2];
#pragma unroll
    for (int rg = 0; rg < 2; rg++) {
      const int row = wrow0 + rg * 16 + fr;
      float xv[8];
      if (row < N) {
        const float4 a = *reinterpret_cast<const float4*>(&x[(size_t)row * IN_F + ks * 32 + fg * 8]);
        const float4 b = *reinterpret_cast<const float4*>(&x[(size_t)row * IN_F + ks * 32 + fg * 8 + 4]);
        xv[0]=a.x; xv[1]=a.y; xv[2]=a.z; xv[3]=a.w;
        xv[4]=b.x; xv[5]=b.y; xv[6]=b.z; xv[7]=b.w;
      } else {
#pragma unroll
        for (int j = 0; j < 8; j++) xv[j] = 0.f;
      }
#pragma unroll
      for (int j = 0; j < 8; j++) {
        const unsigned short h = f2bf(xv[j]);
        const float r = xv[j] - bf2f(h);
        ahi[rg][j] = (short)h;
        alo[rg][j] = (short)f2bf(r);
      }
    }
#pragma unroll
    for (int n = 0; n < 8; n++) {
      const int c = n * 16 + fr;
      const int slot = (((ks * 4 + fg) ^ (c & 7)) * 8);
      const bf16x8 bhi = *reinterpret_cast<const bf16x8*>(&wl[0][c * 128 + slot]);
      const bf16x8 blo = *reinterpret_cast<const bf16x8*>(&wl[1][c * 128 + slot]);
#pragma unroll
      for (int rg = 0; rg < 2; rg++) {
        acc[rg][n] = __builtin_amdgcn_mfma_f32_16x16x32_bf16(ahi[rg], bhi, acc[rg][n], 0, 0, 0);
        acc[rg][n] = __builtin_amdgcn_mfma_f32_16x16x32_bf16(alo[rg], bhi, acc[rg][n], 0, 0, 0);
        acc[rg][n] = __builtin_amdgcn_mfma_f32_16x16x32_bf16(ahi[rg], blo, acc[rg][n], 0, 0, 0);
      }
    }
  }

  const int colbase = ch * 128;
#pragma unroll
  for (int rg = 0; rg < 2; rg++) {
    float psS[2][4], psD[2][4];
#pragma unroll
    for (int h = 0; h < 2; h++)
#pragma unroll
      for (int r = 0; r < 4; r++) { psS[h][r] = 0.f; psD[h][r] = 0.f; }
#pragma unroll
    for (int n = 0; n < 8; n++) {
      const int col = colbase + n * 16 + fr;
      const float as_ = att_s[col];
      const float ad_ = att_d[col];
      const int h = n >> 2;
#pragma unroll
      for (int r = 0; r < 4; r++) {
        psS[h][r] = fmaf(acc[rg][n][r], as_, psS[h][r]);
        psD[h][r] = fmaf(acc[rg][n][r], ad_, psD[h][r]);
      }
    }
#pragma unroll
    for (int h = 0; h < 2; h++)
#pragma unroll
      for (int r = 0; r < 4; r++)
#pragma unroll
        for (int o = 8; o > 0; o >>= 1) {
          psS[h][r] += __shfl_xor(psS[h][r], o, 64);
          psD[h][r] += __shfl_xor(psD[h][r], o, 64);
        }
    if (fr == 0) {
#pragma unroll
      for (int r = 0; r < 4; r++) {
        const int row = wrow0 + rg * 16 + fg * 4 + r;
        if (row < N) {
#pragma unroll
          for (int h = 0; h < 2; h++) {
            as1[(size_t)row * 4 + ch * 2 + h] = psS[h][r];
            ad1[(size_t)row * 4 + ch * 2 + h] = psD[h][r];
          }
        }
      }
    }
#pragma unroll
    for (int r = 0; r < 4; r++) {
      const int row = wrow0 + rg * 16 + fg * 4 + r;
      if (row < N) {
#pragma unroll
        for (int n = 0; n < 8; n++)
          h1b[(size_t)row * 256 + colbase + n * 16 + fr] = f2bf(acc[rg][n][r]);
      }
    }
  }
}

// ---------------- CSR build ----------------
__global__ __launch_bounds__(256) void hist_kernel(const int* __restrict__ dst, int* __restrict__ cnt, int E) {
  const int e = blockIdx.x * 256 + threadIdx.x;
  if (e < E) atomicAdd(&cnt[dst[e]], 1);
}

__global__ __launch_bounds__(256) void block_reduce_kernel(
    const int* __restrict__ cnt, int* __restrict__ bsum, int N) {
  const int i = blockIdx.x * 256 + threadIdx.x;
  int v = (i < N) ? cnt[i] : 0;
#pragma unroll
  for (int o = 32; o > 0; o >>= 1) v += __shfl_xor(v, o, 64);
  __shared__ int ws_[4];
  if ((threadIdx.x & 63) == 0) ws_[threadIdx.x >> 6] = v;
  __syncthreads();
  if (threadIdx.x == 0)
    bsum[blockIdx.x] = ws_[0] + ws_[1] + ws_[2] + ws_[3];
}

__global__ __launch_bounds__(256) void bsum_scan_kernel(
    int* __restrict__ bsum, int* __restrict__ boff, int NB) {
  __shared__ int sdata[256];
  const int t = threadIdx.x;
  int v = (t < NB) ? bsum[t] : 0;
  sdata[t] = v;
  __syncthreads();
  for (int o = 1; o < 256; o <<= 1) {
    int x = (t >= o) ? sdata[t - o] : 0;
    __syncthreads();
    sdata[t] += x;
    __syncthreads();
  }
  if (t < NB) boff[t] = sdata[t] - v;   // exclusive
}

__global__ __launch_bounds__(256) void block_scan_kernel(
    const int* __restrict__ cnt, const int* __restrict__ boff,
    int* __restrict__ row_start, int* __restrict__ cursor, int N) {
  __shared__ int sdata[256];
  const int t = threadIdx.x;
  const int i = blockIdx.x * 256 + t;
  int v = (i < N) ? cnt[i] : 0;
  sdata[t] = v;
  __syncthreads();
  for (int o = 1; o < 256; o <<= 1) {
    int x = (t >= o) ? sdata[t - o] : 0;
    __syncthreads();
    sdata[t] += x;
    __syncthreads();
  }
  if (i < N) {
    const int rs = boff[blockIdx.x] + sdata[t] - v;
    row_start[i] = rs;
    cursor[i] = rs;
    if (i == N - 1) row_start[N] = rs + v;
  }
}

__global__ __launch_bounds__(256) void scatter_kernel(
    const int* __restrict__ src, const int* __restrict__ dst,
    int* __restrict__ cursor, int* __restrict__ csr_src, int E) {
  const int e = blockIdx.x * 256 + threadIdx.x;
  if (e < E) {
    const int d = dst[e];
    const int pos = atomicAdd(&cursor[d], 1);
    csr_src[pos] = src[e];
  }
}

// ---- gather1 FUSED: per-chunk lane-parallel weights -> wave LDS stash -> MLP=4 gather ----
__global__ __launch_bounds__(256) void gather1f_kernel(
    const unsigned short* __restrict__ h1b,
    const float* __restrict__ as1, const float* __restrict__ ad1,
    const float* __restrict__ b1, const int* __restrict__ row_start,
    const int* __restrict__ csr_src, unsigned short* __restrict__ hmidb, int N) {
  __shared__ float wbuf[4][256];    // [wave][edge*4 + head]
  __shared__ int   sbuf[4][64];     // [wave][edge]
  const int lane = threadIdx.x & 63;
  const int wv   = threadIdx.x >> 6;
  const int v = blockIdx.x * 4 + wv;
  if (v >= N) return;
  const int hd = lane >> 4;         // head of this lane's 4 channels
  const int rs = row_start[v], re = row_start[v + 1];
  const float4 adv = *reinterpret_cast<const float4*>(&ad1[(size_t)v * 4]);
  const float4 asv = *reinterpret_cast<const float4*>(&as1[(size_t)v * 4]);
  const float wself_hd = __expf(lrelu(sel4(asv, hd) + sel4(adv, hd)));
  const ushort4 sv = reinterpret_cast<const ushort4*>(h1b + (size_t)v * 256)[lane];
  float4 acc;
  acc.x = wself_hd * bf2f(sv.x); acc.y = wself_hd * bf2f(sv.y);
  acc.z = wself_hd * bf2f(sv.z); acc.w = wself_hd * bf2f(sv.w);
  float4 denp = make_float4(0.f, 0.f, 0.f, 0.f);
  const float* adp = reinterpret_cast<const float*>(&adv);

  for (int base = rs; base < re; base += 64) {
    const int cnt = min(64, re - base);
    int s = v;
    float4 w4 = make_float4(0.f, 0.f, 0.f, 0.f);
    if (lane < cnt) {
      s = csr_src[base + lane];
      const float4 av = *reinterpret_cast<const float4*>(&as1[(size_t)s * 4]);
      const float* ap = reinterpret_cast<const float*>(&av);
      float* wp = reinterpret_cast<float*>(&w4);
#pragma unroll
      for (int h = 0; h < HEADS; h++) wp[h] = __expf(lrelu(ap[h] + adp[h]));
      denp.x += w4.x; denp.y += w4.y; denp.z += w4.z; denp.w += w4.w;
    }
    sbuf[wv][lane] = s;
    *reinterpret_cast<float4*>(&wbuf[wv][lane * 4]) = w4;
    const int cntp = (cnt + 3) & ~3;
    for (int j = 0; j < cntp; j += 4) {
      const int s0 = sbuf[wv][j],     s1 = sbuf[wv][j + 1];
      const int s2 = sbuf[wv][j + 2], s3 = sbuf[wv][j + 3];
      const float y0 = wbuf[wv][(j) * 4 + hd];
      const float y1 = wbuf[wv][(j + 1) * 4 + hd];
      const float y2 = wbuf[wv][(j + 2) * 4 + hd];
      const float y3 = wbuf[wv][(j + 3) * 4 + hd];
      const ushort4 f0 = reinterpret_cast<const ushort4*>(h1b + (size_t)s0 * 256)[lane];
      const ushort4 f1 = reinterpret_cast<const ushort4*>(h1b + (size_t)s1 * 256)[lane];
      const ushort4 f2 = reinterpret_cast<const ushort4*>(h1b + (size_t)s2 * 256)[lane];
      const ushort4 f3 = reinterpret_cast<const ushort4*>(h1b + (size_t)s3 * 256)[lane];
      acc.x = fmaf(y0, bf2f(f0.x), acc.x); acc.y = fmaf(y0, bf2f(f0.y), acc.y);
      acc.z = fmaf(y0, bf2f(f0.z), acc.z); acc.w = fmaf(y0, bf2f(f0.w), acc.w);
      acc.x = fmaf(y1, bf2f(f1.x), acc.x); acc.y = fmaf(y1, bf2f(f1.y), acc.y);
      acc.z = fmaf(y1, bf2f(f1.z), acc.z); acc.w = fmaf(y1, bf2f(f1.w), acc.w);
      acc.x = fmaf(y2, bf2f(f2.x), acc.x); acc.y = fmaf(y2, bf2f(f2.y), acc.y);
      acc.z = fmaf(y2, bf2f(f2.z), acc.z); acc.w = fmaf(y2, bf2f(f2.w), acc.w);
      acc.x = fmaf(y3, bf2f(f3.x), acc.x); acc.y = fmaf(y3, bf2f(f3.y), acc.y);
      acc.z = fmaf(y3, bf2f(f3.z), acc.z); acc.w = fmaf(y3, bf2f(f3.w), acc.w);
    }
  }
#pragma unroll
  for (int o = 32; o > 0; o >>= 1) {
    denp.x += __shfl_xor(denp.x, o, 64);
    denp.y += __shfl_xor(denp.y, o, 64);
    denp.z += __shfl_xor(denp.z, o, 64);
    denp.w += __shfl_xor(denp.w, o, 64);
  }
  const float wi = 1.f / (sel4(denp, hd) + wself_hd + EPS_SM);
  const float4 bv = *reinterpret_cast<const float4*>(&b1[lane * 4]);
  ushort4 ov;
  ov.x = f2bf(elu1(acc.x * wi + bv.x));
  ov.y = f2bf(elu1(acc.y * wi + bv.y));
  ov.z = f2bf(elu1(acc.z * wi + bv.z));
  ov.w = f2bf(elu1(acc.w * wi + bv.w));
  reinterpret_cast<ushort4*>(hmidb + (size_t)v * 256)[lane] = ov;
}

// ---- GEMM2 via MFMA: h2b[N,64](bf16) = hmidb(bf16) @ W2(hi/lo LDS) ; fused alpha2 ----
// 512 thr / 8 waves; block = 128 rows; wave = 16 rows x 64 cols; K=256 in 8 steps.
// A is exactly bf16 -> no A-split; B hi/lo -> 2 MFMAs/tile (fp32-equivalent).
__global__ __launch_bounds__(512) void gemm2_mfma_kernel(
    const unsigned short* __restrict__ A,
    const unsigned short* __restrict__ W2Thi, const unsigned short* __restrict__ W2Tlo,
    const float* __restrict__ att_s, const float* __restrict__ att_d,
    unsigned short* __restrict__ h2b, float* __restrict__ as2, float* __restrict__ ad2, int N) {
  __shared__ unsigned short wl[2][64 * 256];    // [hi/lo][col][k], 16B-chunk swizzled
  const int tid = threadIdx.x;
#pragma unroll
  for (int it = 0; it < 8; ++it) {
    const int idx = it * 512 + tid;             // 0..4095
    const unsigned short* srcp = (it < 4) ? W2Thi : W2Tlo;
    const int arr = (it < 4) ? 0 : 1;
    const int rem = idx & 2047;
    const int c = rem >> 5;                     // col 0..63
    const int j = rem & 31;                     // 16B chunk 0..31
    const uint4 v = *reinterpret_cast<const uint4*>(&srcp[(size_t)c * 256 + j * 8]);
    *reinterpret_cast<uint4*>(&wl[arr][c * 256 + ((j ^ (c & 7)) * 8)]) = v;
  }
  __syncthreads();

  const int lane = tid & 63;
  const int wid  = tid >> 6;                    // 0..7
  const int fr = lane & 15;
  const int fg = lane >> 4;
  const int wrow0 = blockIdx.x * 128 + wid * 16;
  const int myrow = wrow0 + fr;
  const bool rok = myrow < N;

  f32x4 acc[4];
#pragma unroll
  for (int n = 0; n < 4; n++) acc[n] = (f32x4){0.f, 0.f, 0.f, 0.f};

#pragma unroll
  for (int ks = 0; ks < 8; ks++) {
    bf16x8 a;
    if (rok) {
      a = *reinterpret_cast<const bf16x8*>(&A[(size_t)myrow * 256 + ks * 32 + fg * 8]);
    } else {
#pragma unroll
      for (int j = 0; j < 8; j++) a[j] = 0;
    }
#pragma unroll
    for (int n = 0; n < 4; n++) {
      const int c = n * 16 + fr;
      const int slot = (((ks * 4 + fg) ^ (c & 7)) * 8);
      const bf16x8 bhi = *reinterpret_cast<const bf16x8*>(&wl[0][c * 256 + slot]);
      const bf16x8 blo = *reinterpret_cast<const bf16x8*>(&wl[1][c * 256 + slot]);
      acc[n] = __builtin_amdgcn_mfma_f32_16x16x32_bf16(a, bhi, acc[n], 0, 0, 0);
      acc[n] = __builtin_amdgcn_mfma_f32_16x16x32_bf16(a, blo, acc[n], 0, 0, 0);
    }
  }

  // fused alpha2 + bf16 store. C/D: col = n*16+fr, row = wrow0 + fg*4 + r.
  float psS[4] = {0.f, 0.f, 0.f, 0.f}, psD[4] = {0.f, 0.f, 0.f, 0.f};
#pragma unroll
  for (int n = 0; n < 4; n++) {
    const int col = n * 16 + fr;
    const float as_ = att_s[col];
    const float ad_ = att_d[col];
#pragma unroll
    for (int r = 0; r < 4; r++) {
      psS[r] = fmaf(acc[n][r], as_, psS[r]);
      psD[r] = fmaf(acc[n][r], ad_, psD[r]);
    }
  }
#pragma unroll
  for (int r = 0; r < 4; r++)
#pragma unroll
    for (int o = 8; o > 0; o >>= 1) {
      psS[r] += __shfl_xor(psS[r], o, 64);
      psD[r] += __shfl_xor(psD[r], o, 64);
    }
  if (fr == 0) {
#pragma unroll
    for (int r = 0; r < 4; r++) {
      const int row = wrow0 + fg * 4 + r;
      if (row < N) { as2[row] = psS[r]; ad2[row] = psD[r]; }
    }
  }
#pragma unroll
  for (int r = 0; r < 4; r++) {
    const int row = wrow0 + fg * 4 + r;
    if (row < N) {
#pragma unroll
      for (int n = 0; n < 4; n++)
        h2b[(size_t)row * 64 + n * 16 + fr] = f2bf(acc[n][r]);
    }
  }
}

// ---- gather2 FUSED: lane-parallel weights -> wave LDS stash -> half-wave MLP=4 gather ----
__global__ __launch_bounds__(256) void gather2f_kernel(
    const unsigned short* __restrict__ h2b,
    const float* __restrict__ as2, const float* __restrict__ ad2,
    const float* __restrict__ b2, const int* __restrict__ row_start,
    const int* __restrict__ csr_src, float* __restrict__ h2, int N) {
  __shared__ float wbuf[4][64];
  __shared__ int   sbuf[4][64];
  const int lane = threadIdx.x & 63;
  const int wv   = threadIdx.x >> 6;
  const int v = blockIdx.x * 4 + wv;
  if (v >= N) return;
  const int half = lane >> 5;
  const int cl = lane & 31;
  const int rs = row_start[v], re = row_start[v + 1];
  const float adv = ad2[v];
  const float wself = __expf(lrelu(as2[v] + adv));
  float ax = 0.f, ay = 0.f;
  if (half == 0) {
    const unsigned int u = reinterpret_cast<const unsigned int*>(h2b + (size_t)v * 64)[cl];
    ax = wself * bf2f(u & 0xffffu);
    ay = wself * bf2f(u >> 16);
  }
  float denp = 0.f;
  for (int base = rs; base < re; base += 64) {
    const int cnt = min(64, re - base);
    int s = v;
    float w = 0.f;
    if (lane < cnt) {
      s = csr_src[base + lane];
      w = __expf(lrelu(as2[s] + adv));
      denp += w;
    }
    sbuf[wv][lane] = s;
    wbuf[wv][lane] = w;
    const int cntp = (cnt + 7) & ~7;
    for (int j = 0; j < cntp; j += 8) {
      const int b0 = j + half;
      const int s0 = sbuf[wv][b0],     s1 = sbuf[wv][b0 + 2];
      const int s2 = sbuf[wv][b0 + 4], s3 = sbuf[wv][b0 + 6];
      const float y0 = wbuf[wv][b0],     y1 = wbuf[wv][b0 + 2];
      const float y2 = wbuf[wv][b0 + 4], y3 = wbuf[wv][b0 + 6];
      const unsigned int f0 = reinterpret_cast<const unsigned int*>(h2b + (size_t)s0 * 64)[cl];
      const unsigned int f1 = reinterpret_cast<const unsigned int*>(h2b + (size_t)s1 * 64)[cl];
      const unsigned int f2 = reinterpret_cast<const unsigned int*>(h2b + (size_t)s2 * 64)[cl];
      const unsigned int f3 = reinterpret_cast<const unsigned int*>(h2b + (size_t)s3 * 64)[cl];
      ax = fmaf(y0, bf2f(f0 & 0xffffu), ax); ay = fmaf(y0, bf2f(f0 >> 16), ay);
      ax = fmaf(y1, bf2f(f1 & 0xffffu), ax); ay = fmaf(y1, bf2f(f1 >> 16), ay);
      ax = fmaf(y2, bf2f(f2 & 0xffffu), ax); ay = fmaf(y2, bf2f(f2 >> 16), ay);
      ax = fmaf(y3, bf2f(f3 & 0xffffu), ax); ay = fmaf(y3, bf2f(f3 >> 16), ay);
    }
  }
#pragma unroll
  for (int o = 32; o > 0; o >>= 1) denp += __shfl_xor(denp, o, 64);
  ax += __shfl_xor(ax, 32, 64);
  ay += __shfl_xor(ay, 32, 64);
  if (half == 0) {
    const float wi = 1.f / (denp + wself + EPS_SM);
    float2 o;
    o.x = elu1(ax * wi + b2[2 * cl]);
    o.y = elu1(ay * wi + b2[2 * cl + 1]);
    reinterpret_cast<float2*>(h2 + (size_t)v * 64)[cl] = o;
  }
}

// ---------------- mean-pool over sorted batch ----------------
__global__ __launch_bounds__(256) void pool_kernel(
    const float* __restrict__ h2, const int* __restrict__ batch,
    float* __restrict__ pooled, float* __restrict__ cntf, int N) {
  const int lane = threadIdx.x & 63;
  const int gw = blockIdx.x * 4 + (threadIdx.x >> 6);
  const int s = gw * 64;
  if (s >= N) return;
  const int e = min(s + 64, N);
  int cur = batch[s];
  float racc = 0.f;
  int rc = 0;
  for (int v = s; v < e; v++) {
    const int g = batch[v];
    if (g != cur) {
      atomicAdd(&pooled[(size_t)cur * 64 + lane], racc);
      if (lane == 0) atomicAdd(&cntf[cur], (float)rc);
      racc = 0.f; rc = 0; cur = g;
    }
    racc += h2[(size_t)v * 64 + lane];
    rc++;
  }
  atomicAdd(&pooled[(size_t)cur * 64 + lane], racc);
  if (lane == 0) atomicAdd(&cntf[cur], (float)rc);
}

// ---------------- classifier ----------------
__global__ __launch_bounds__(64) void final_kernel(
    const float* __restrict__ pooled, const float* __restrict__ cntf,
    const float* __restrict__ Wc, const float* __restrict__ bc, float* __restrict__ out) {
  const int g = threadIdx.x;
  float acc = 0.f;
  for (int c = 0; c < 64; c++) acc = fmaf(pooled[(size_t)g * 64 + c], Wc[c], acc);
  const float cnt = fmaxf(cntf[g], 1.0f);
  out[g] = acc / cnt + bc[0];
}

extern "C" void kernel_launch(void* const* d_in, const int* in_sizes, int n_in,
                              void* d_out, int out_size, void* d_ws, size_t ws_size,
                              hipStream_t stream) {
  const float* x     = (const float*)d_in[0];
  const int*   ei    = (const int*)d_in[1];
  const int*   batch = (const int*)d_in[2];
  const float* W1    = (const float*)d_in[3];
  const float* atts1 = (const float*)d_in[4];
  const float* attd1 = (const float*)d_in[5];
  const float* b1    = (const float*)d_in[6];
  const float* W2    = (const float*)d_in[7];
  const float* atts2 = (const float*)d_in[8];
  const float* attd2 = (const float*)d_in[9];
  const float* b2    = (const float*)d_in[10];
  const float* Wc    = (const float*)d_in[11];
  const float* bc    = (const float*)d_in[12];
  float* out = (float*)d_out;

  const int N = in_sizes[0] / IN_F;   // 50000
  const int E = in_sizes[1] / 2;      // 800000
  const int* src = ei;
  const int* dst = ei + E;
  const int NB = (N + 255) / 256;     // scan blocks
  const int NRT = (N + 255) / 256;    // gemm1 row tiles

  char* ws = (char*)d_ws;
  size_t off = 0;
  auto take = [&](size_t bytes) -> void* {
    void* p = ws + off;
    off = (off + bytes + 255) & ~(size_t)255;
    return p;
  };
  unsigned short* h1b   = (unsigned short*)take((size_t)N * 256 * 2);
  unsigned short* hmidb = (unsigned short*)take((size_t)N * 256 * 2);
  unsigned short* h2b   = (unsigned short*)take((size_t)N * 64 * 2);
  unsigned short* wthi  = (unsigned short*)take((size_t)256 * 128 * 2);
  unsigned short* wtlo  = (unsigned short*)take((size_t)256 * 128 * 2);
  unsigned short* w2thi = (unsigned short*)take((size_t)64 * 256 * 2);
  unsigned short* w2tlo = (unsigned short*)take((size_t)64 * 256 * 2);
  float* as1      = (float*)take((size_t)N * 4 * sizeof(float));
  float* ad1      = (float*)take((size_t)N * 4 * sizeof(float));
  float* as2      = (float*)take((size_t)N * sizeof(float));
  float* ad2      = (float*)take((size_t)N * sizeof(float));
  int*   cnt      = (int*)take((size_t)N * sizeof(int));
  int*   row_start= (int*)take((size_t)(N + 1) * sizeof(int));
  int*   cursor   = (int*)take((size_t)N * sizeof(int));
  int*   csr_src  = (int*)take((size_t)E * sizeof(int));
  int*   bsum     = (int*)take((size_t)NB * sizeof(int));
  int*   boff     = (int*)take((size_t)NB * sizeof(int));
  float* pooled   = (float*)take((size_t)GROUPS * 64 * sizeof(float));
  float* cntf     = (float*)take((size_t)GROUPS * sizeof(float));
  float* h2       = (float*)take((size_t)N * 64 * sizeof(float));

  hipMemsetAsync(cnt, 0, (size_t)N * sizeof(int), stream);
  hipMemsetAsync(pooled, 0, (size_t)GROUPS * 64 * sizeof(float), stream);
  hipMemsetAsync(cntf, 0, (size_t)GROUPS * sizeof(float), stream);

  // weight prep (tiny)
  prep_w1_kernel<<<128, 256, 0, stream>>>(W1, wthi, wtlo);
  prep_w2_kernel<<<64, 256, 0, stream>>>(W2, w2thi, w2tlo);

  // conv1 linear (MFMA) + fused attention coefficients
  gemm1_mfma_kernel<<<NRT * 2, 512, 0, stream>>>(x, wthi, wtlo, atts1, attd1, h1b, as1, ad1, N);

  // CSR by dst (multi-block scan)
  hist_kernel<<<(E + 255) / 256, 256, 0, stream>>>(dst, cnt, E);
  block_reduce_kernel<<<NB, 256, 0, stream>>>(cnt, bsum, N);
  bsum_scan_kernel<<<1, 256, 0, stream>>>(bsum, boff, NB);
  block_scan_kernel<<<NB, 256, 0, stream>>>(cnt, boff, row_start, cursor, N);
  scatter_kernel<<<(E + 255) / 256, 256, 0, stream>>>(src, dst, cursor, csr_src, E);

  // conv1 aggregate (weights fused in)
  gather1f_kernel<<<(N + 3) / 4, 256, 0, stream>>>(h1b, as1, ad1, b1, row_start, csr_src, hmidb, N);

  // conv2 (MFMA) + aggregate
  gemm2_mfma_kernel<<<(N + 127) / 128, 512, 0, stream>>>(hmidb, w2thi, w2tlo, atts2, attd2, h2b, as2, ad2, N);
  gather2f_kernel<<<(N + 3) / 4, 256, 0, stream>>>(h2b, as2, ad2, b2, row_start, csr_src, h2, N);

  // pooling + classifier
  pool_kernel<<<((N + 63) / 64 + 3) / 4, 256, 0, stream>>>(h2, batch, pooled, cntf, N);
  final_kernel<<<1, 64, 0, stream>>>(pooled, cntf, Wc, bc, out);

  (void)n_in; (void)out_size; (void)ws_size;
}

// Round 12
// 203.841 us; speedup vs baseline: 1.8208x; 1.3019x over previous
//
#include <hip/hip_runtime.h>
#include <hip/hip_bf16.h>

constexpr int HEADS  = 4;
constexpr int HID    = 64;
constexpr int IN_F   = 128;
constexpr int GROUPS = 64;
constexpr float NEG_SLOPE = 0.2f;
constexpr float EPS_SM    = 1e-16f;

typedef short bf16x8 __attribute__((ext_vector_type(8)));
typedef float f32x4  __attribute__((ext_vector_type(4)));

static __device__ __forceinline__ float lrelu(float x) { return x >= 0.f ? x : NEG_SLOPE * x; }
static __device__ __forceinline__ float elu1(float x)  { return x > 0.f ? x : expm1f(x); }

static __device__ __forceinline__ float bf2f(unsigned int u) {
  union { unsigned int i; float f; } x; x.i = u << 16; return x.f;
}
static __device__ __forceinline__ unsigned short f2bf(float f) {
  union { float f; unsigned int i; } x; x.f = f;
  unsigned int lsb = (x.i >> 16) & 1u;
  x.i += 0x7fffu + lsb;
  return (unsigned short)(x.i >> 16);
}
static __device__ __forceinline__ float sel4(float4 v, int i) {
  return i == 0 ? v.x : (i == 1 ? v.y : (i == 2 ? v.z : v.w));
}

// ---- prep (combined): W1T_hi/lo[256][128] and W2T_hi/lo[64][256] ----
__global__ __launch_bounds__(256) void prep_w_kernel(
    const float* __restrict__ W1, unsigned short* __restrict__ W1Thi, unsigned short* __restrict__ W1Tlo,
    const float* __restrict__ W2, unsigned short* __restrict__ W2Thi, unsigned short* __restrict__ W2Tlo) {
  if (blockIdx.x < 128) {
    const int k = blockIdx.x;            // 0..127
    const int n = threadIdx.x;           // 0..255
    const float w = W1[(size_t)k * 256 + n];
    const unsigned short hi = f2bf(w);
    W1Thi[(size_t)n * 128 + k] = hi;
    W1Tlo[(size_t)n * 128 + k] = f2bf(w - bf2f(hi));
  } else {
    const int n = blockIdx.x - 128;      // 0..63
    const int k = threadIdx.x;           // 0..255
    const float w = W2[(size_t)k * 64 + n];
    const unsigned short hi = f2bf(w);
    W2Thi[(size_t)n * 256 + k] = hi;
    W2Tlo[(size_t)n * 256 + k] = f2bf(w - bf2f(hi));
  }
}

// ---- GEMM1 via MFMA (blocks < G1) + histogram-with-rank (blocks >= G1) ----
__global__ __launch_bounds__(512) void gemm1_hist_kernel(
    const float* __restrict__ x,
    const unsigned short* __restrict__ WThi, const unsigned short* __restrict__ WTlo,
    const float* __restrict__ att_s, const float* __restrict__ att_d,
    unsigned short* __restrict__ h1b, float* __restrict__ as1, float* __restrict__ ad1, int N,
    const int* __restrict__ dst, int* __restrict__ cnt, int* __restrict__ rank, int E, int G1) {
  __shared__ unsigned short wl[2][128 * 128];   // [hi/lo][col][k], 16B-chunk swizzled
  const int tid = threadIdx.x;

  if (blockIdx.x >= G1) {                       // --- histogram part ---
    const int e = (blockIdx.x - G1) * 512 + tid;
    if (e < E) rank[e] = atomicAdd(&cnt[dst[e]], 1);
    return;
  }

  const int rowtile = blockIdx.x >> 1;
  const int ch = blockIdx.x & 1;                // column half (cols ch*128 .. +127)

#pragma unroll
  for (int it = 0; it < 8; ++it) {
    const int idx = it * 512 + tid;             // 0..4095
    const unsigned short* srcp = (it < 4) ? WThi : WTlo;
    const int arr = (it < 4) ? 0 : 1;
    const int rem = idx & 2047;
    const int c = rem >> 4;                     // local col 0..127
    const int j = rem & 15;                     // 16B chunk 0..15
    const uint4 v = *reinterpret_cast<const uint4*>(
        &srcp[((size_t)(ch * 128 + c)) * 128 + j * 8]);
    *reinterpret_cast<uint4*>(&wl[arr][c * 128 + ((j ^ (c & 7)) * 8)]) = v;
  }
  __syncthreads();

  const int lane = tid & 63;
  const int wid  = tid >> 6;                    // 0..7
  const int fr = lane & 15;
  const int fg = lane >> 4;
  const int wrow0 = rowtile * 256 + wid * 32;

  f32x4 acc[2][8];
#pragma unroll
  for (int rg = 0; rg < 2; rg++)
#pragma unroll
    for (int n = 0; n < 8; n++) acc[rg][n] = (f32x4){0.f, 0.f, 0.f, 0.f};

#pragma unroll
  for (int ks = 0; ks < 4; ks++) {
    bf16x8 ahi[2], alo[2];
#pragma unroll
    for (int rg = 0; rg < 2; rg++) {
      const int row = wrow0 + rg * 16 + fr;
      float xv[8];
      if (row < N) {
        const float4 a = *reinterpret_cast<const float4*>(&x[(size_t)row * IN_F + ks * 32 + fg * 8]);
        const float4 b = *reinterpret_cast<const float4*>(&x[(size_t)row * IN_F + ks * 32 + fg * 8 + 4]);
        xv[0]=a.x; xv[1]=a.y; xv[2]=a.z; xv[3]=a.w;
        xv[4]=b.x; xv[5]=b.y; xv[6]=b.z; xv[7]=b.w;
      } else {
#pragma unroll
        for (int j = 0; j < 8; j++) xv[j] = 0.f;
      }
#pragma unroll
      for (int j = 0; j < 8; j++) {
        const unsigned short h = f2bf(xv[j]);
        const float r = xv[j] - bf2f(h);
        ahi[rg][j] = (short)h;
        alo[rg][j] = (short)f2bf(r);
      }
    }
#pragma unroll
    for (int n = 0; n < 8; n++) {
      const int c = n * 16 + fr;
      const int slot = (((ks * 4 + fg) ^ (c & 7)) * 8);
      const bf16x8 bhi = *reinterpret_cast<const bf16x8*>(&wl[0][c * 128 + slot]);
      const bf16x8 blo = *reinterpret_cast<const bf16x8*>(&wl[1][c * 128 + slot]);
#pragma unroll
      for (int rg = 0; rg < 2; rg++) {
        acc[rg][n] = __builtin_amdgcn_mfma_f32_16x16x32_bf16(ahi[rg], bhi, acc[rg][n], 0, 0, 0);
        acc[rg][n] = __builtin_amdgcn_mfma_f32_16x16x32_bf16(alo[rg], bhi, acc[rg][n], 0, 0, 0);
        acc[rg][n] = __builtin_amdgcn_mfma_f32_16x16x32_bf16(ahi[rg], blo, acc[rg][n], 0, 0, 0);
      }
    }
  }

  const int colbase = ch * 128;
#pragma unroll
  for (int rg = 0; rg < 2; rg++) {
    float psS[2][4], psD[2][4];
#pragma unroll
    for (int h = 0; h < 2; h++)
#pragma unroll
      for (int r = 0; r < 4; r++) { psS[h][r] = 0.f; psD[h][r] = 0.f; }
#pragma unroll
    for (int n = 0; n < 8; n++) {
      const int col = colbase + n * 16 + fr;
      const float as_ = att_s[col];
      const float ad_ = att_d[col];
      const int h = n >> 2;
#pragma unroll
      for (int r = 0; r < 4; r++) {
        psS[h][r] = fmaf(acc[rg][n][r], as_, psS[h][r]);
        psD[h][r] = fmaf(acc[rg][n][r], ad_, psD[h][r]);
      }
    }
#pragma unroll
    for (int h = 0; h < 2; h++)
#pragma unroll
      for (int r = 0; r < 4; r++)
#pragma unroll
        for (int o = 8; o > 0; o >>= 1) {
          psS[h][r] += __shfl_xor(psS[h][r], o, 64);
          psD[h][r] += __shfl_xor(psD[h][r], o, 64);
        }
    if (fr == 0) {
#pragma unroll
      for (int r = 0; r < 4; r++) {
        const int row = wrow0 + rg * 16 + fg * 4 + r;
        if (row < N) {
#pragma unroll
          for (int h = 0; h < 2; h++) {
            as1[(size_t)row * 4 + ch * 2 + h] = psS[h][r];
            ad1[(size_t)row * 4 + ch * 2 + h] = psD[h][r];
          }
        }
      }
    }
#pragma unroll
    for (int r = 0; r < 4; r++) {
      const int row = wrow0 + rg * 16 + fg * 4 + r;
      if (row < N) {
#pragma unroll
        for (int n = 0; n < 8; n++)
          h1b[(size_t)row * 256 + colbase + n * 16 + fr] = f2bf(acc[rg][n][r]);
      }
    }
  }
}

// ---------------- multi-block scan ----------------
__global__ __launch_bounds__(256) void block_reduce_kernel(
    const int* __restrict__ cnt, int* __restrict__ bsum, int N) {
  const int i = blockIdx.x * 256 + threadIdx.x;
  int v = (i < N) ? cnt[i] : 0;
#pragma unroll
  for (int o = 32; o > 0; o >>= 1) v += __shfl_xor(v, o, 64);
  __shared__ int ws_[4];
  if ((threadIdx.x & 63) == 0) ws_[threadIdx.x >> 6] = v;
  __syncthreads();
  if (threadIdx.x == 0)
    bsum[blockIdx.x] = ws_[0] + ws_[1] + ws_[2] + ws_[3];
}

__global__ __launch_bounds__(256) void bsum_scan_kernel(
    int* __restrict__ bsum, int* __restrict__ boff, int NB) {
  __shared__ int sdata[256];
  const int t = threadIdx.x;
  int v = (t < NB) ? bsum[t] : 0;
  sdata[t] = v;
  __syncthreads();
  for (int o = 1; o < 256; o <<= 1) {
    int x = (t >= o) ? sdata[t - o] : 0;
    __syncthreads();
    sdata[t] += x;
    __syncthreads();
  }
  if (t < NB) boff[t] = sdata[t] - v;   // exclusive
}

__global__ __launch_bounds__(256) void block_scan_kernel(
    const int* __restrict__ cnt, const int* __restrict__ boff,
    int* __restrict__ row_start, int N) {
  __shared__ int sdata[256];
  const int t = threadIdx.x;
  const int i = blockIdx.x * 256 + t;
  int v = (i < N) ? cnt[i] : 0;
  sdata[t] = v;
  __syncthreads();
  for (int o = 1; o < 256; o <<= 1) {
    int x = (t >= o) ? sdata[t - o] : 0;
    __syncthreads();
    sdata[t] += x;
    __syncthreads();
  }
  if (i < N) {
    const int rs = boff[blockIdx.x] + sdata[t] - v;
    row_start[i] = rs;
    if (i == N - 1) row_start[N] = rs + v;
  }
}

// ---- scatter without atomics: position = row_start[dst] + rank ----
__global__ __launch_bounds__(256) void scatter_kernel(
    const int* __restrict__ src, const int* __restrict__ dst,
    const int* __restrict__ row_start, const int* __restrict__ rank,
    int* __restrict__ csr_src, int E) {
  const int e = blockIdx.x * 256 + threadIdx.x;
  if (e < E) {
    const int pos = row_start[dst[e]] + rank[e];
    csr_src[pos] = src[e];
  }
}

// ---- gather1 FUSED: per-chunk lane-parallel weights -> wave LDS stash -> MLP=4 gather ----
__global__ __launch_bounds__(256) void gather1f_kernel(
    const unsigned short* __restrict__ h1b,
    const float* __restrict__ as1, const float* __restrict__ ad1,
    const float* __restrict__ b1, const int* __restrict__ row_start,
    const int* __restrict__ csr_src, unsigned short* __restrict__ hmidb, int N) {
  __shared__ float wbuf[4][256];    // [wave][edge*4 + head]
  __shared__ int   sbuf[4][64];     // [wave][edge]
  const int lane = threadIdx.x & 63;
  const int wv   = threadIdx.x >> 6;
  const int v = blockIdx.x * 4 + wv;
  if (v >= N) return;
  const int hd = lane >> 4;         // head of this lane's 4 channels
  const int rs = row_start[v], re = row_start[v + 1];
  const float4 adv = *reinterpret_cast<const float4*>(&ad1[(size_t)v * 4]);
  const float4 asv = *reinterpret_cast<const float4*>(&as1[(size_t)v * 4]);
  const float wself_hd = __expf(lrelu(sel4(asv, hd) + sel4(adv, hd)));
  const ushort4 sv = reinterpret_cast<const ushort4*>(h1b + (size_t)v * 256)[lane];
  float4 acc;
  acc.x = wself_hd * bf2f(sv.x); acc.y = wself_hd * bf2f(sv.y);
  acc.z = wself_hd * bf2f(sv.z); acc.w = wself_hd * bf2f(sv.w);
  float4 denp = make_float4(0.f, 0.f, 0.f, 0.f);
  const float* adp = reinterpret_cast<const float*>(&adv);

  for (int base = rs; base < re; base += 64) {
    const int cnt = min(64, re - base);
    int s = v;
    float4 w4 = make_float4(0.f, 0.f, 0.f, 0.f);
    if (lane < cnt) {
      s = csr_src[base + lane];
      const float4 av = *reinterpret_cast<const float4*>(&as1[(size_t)s * 4]);
      const float* ap = reinterpret_cast<const float*>(&av);
      float* wp = reinterpret_cast<float*>(&w4);
#pragma unroll
      for (int h = 0; h < HEADS; h++) wp[h] = __expf(lrelu(ap[h] + adp[h]));
      denp.x += w4.x; denp.y += w4.y; denp.z += w4.z; denp.w += w4.w;
    }
    sbuf[wv][lane] = s;
    *reinterpret_cast<float4*>(&wbuf[wv][lane * 4]) = w4;
    const int cntp = (cnt + 3) & ~3;
    for (int j = 0; j < cntp; j += 4) {
      const int s0 = sbuf[wv][j],     s1 = sbuf[wv][j + 1];
      const int s2 = sbuf[wv][j + 2], s3 = sbuf[wv][j + 3];
      const float y0 = wbuf[wv][(j) * 4 + hd];
      const float y1 = wbuf[wv][(j + 1) * 4 + hd];
      const float y2 = wbuf[wv][(j + 2) * 4 + hd];
      const float y3 = wbuf[wv][(j + 3) * 4 + hd];
      const ushort4 f0 = reinterpret_cast<const ushort4*>(h1b + (size_t)s0 * 256)[lane];
      const ushort4 f1 = reinterpret_cast<const ushort4*>(h1b + (size_t)s1 * 256)[lane];
      const ushort4 f2 = reinterpret_cast<const ushort4*>(h1b + (size_t)s2 * 256)[lane];
      const ushort4 f3 = reinterpret_cast<const ushort4*>(h1b + (size_t)s3 * 256)[lane];
      acc.x = fmaf(y0, bf2f(f0.x), acc.x); acc.y = fmaf(y0, bf2f(f0.y), acc.y);
      acc.z = fmaf(y0, bf2f(f0.z), acc.z); acc.w = fmaf(y0, bf2f(f0.w), acc.w);
      acc.x = fmaf(y1, bf2f(f1.x), acc.x); acc.y = fmaf(y1, bf2f(f1.y), acc.y);
      acc.z = fmaf(y1, bf2f(f1.z), acc.z); acc.w = fmaf(y1, bf2f(f1.w), acc.w);
      acc.x = fmaf(y2, bf2f(f2.x), acc.x); acc.y = fmaf(y2, bf2f(f2.y), acc.y);
      acc.z = fmaf(y2, bf2f(f2.z), acc.z); acc.w = fmaf(y2, bf2f(f2.w), acc.w);
      acc.x = fmaf(y3, bf2f(f3.x), acc.x); acc.y = fmaf(y3, bf2f(f3.y), acc.y);
      acc.z = fmaf(y3, bf2f(f3.z), acc.z); acc.w = fmaf(y3, bf2f(f3.w), acc.w);
    }
  }
#pragma unroll
  for (int o = 32; o > 0; o >>= 1) {
    denp.x += __shfl_xor(denp.x, o, 64);
    denp.y += __shfl_xor(denp.y, o, 64);
    denp.z += __shfl_xor(denp.z, o, 64);
    denp.w += __shfl_xor(denp.w, o, 64);
  }
  const float wi = 1.f / (sel4(denp, hd) + wself_hd + EPS_SM);
  const float4 bv = *reinterpret_cast<const float4*>(&b1[lane * 4]);
  ushort4 ov;
  ov.x = f2bf(elu1(acc.x * wi + bv.x));
  ov.y = f2bf(elu1(acc.y * wi + bv.y));
  ov.z = f2bf(elu1(acc.z * wi + bv.z));
  ov.w = f2bf(elu1(acc.w * wi + bv.w));
  reinterpret_cast<ushort4*>(hmidb + (size_t)v * 256)[lane] = ov;
}

// ---- GEMM2 via MFMA: h2b[N,64](bf16) = hmidb(bf16) @ W2(hi/lo LDS) ; fused alpha2 ----
__global__ __launch_bounds__(512) void gemm2_mfma_kernel(
    const unsigned short* __restrict__ A,
    const unsigned short* __restrict__ W2Thi, const unsigned short* __restrict__ W2Tlo,
    const float* __restrict__ att_s, const float* __restrict__ att_d,
    unsigned short* __restrict__ h2b, float* __restrict__ as2, float* __restrict__ ad2, int N) {
  __shared__ unsigned short wl[2][64 * 256];    // [hi/lo][col][k], 16B-chunk swizzled
  const int tid = threadIdx.x;
#pragma unroll
  for (int it = 0; it < 8; ++it) {
    const int idx = it * 512 + tid;             // 0..4095
    const unsigned short* srcp = (it < 4) ? W2Thi : W2Tlo;
    const int arr = (it < 4) ? 0 : 1;
    const int rem = idx & 2047;
    const int c = rem >> 5;                     // col 0..63
    const int j = rem & 31;                     // 16B chunk 0..31
    const uint4 v = *reinterpret_cast<const uint4*>(&srcp[(size_t)c * 256 + j * 8]);
    *reinterpret_cast<uint4*>(&wl[arr][c * 256 + ((j ^ (c & 7)) * 8)]) = v;
  }
  __syncthreads();

  const int lane = tid & 63;
  const int wid  = tid >> 6;                    // 0..7
  const int fr = lane & 15;
  const int fg = lane >> 4;
  const int wrow0 = blockIdx.x * 128 + wid * 16;
  const int myrow = wrow0 + fr;
  const bool rok = myrow < N;

  f32x4 acc[4];
#pragma unroll
  for (int n = 0; n < 4; n++) acc[n] = (f32x4){0.f, 0.f, 0.f, 0.f};

#pragma unroll
  for (int ks = 0; ks < 8; ks++) {
    bf16x8 a;
    if (rok) {
      a = *reinterpret_cast<const bf16x8*>(&A[(size_t)myrow * 256 + ks * 32 + fg * 8]);
    } else {
#pragma unroll
      for (int j = 0; j < 8; j++) a[j] = 0;
    }
#pragma unroll
    for (int n = 0; n < 4; n++) {
      const int c = n * 16 + fr;
      const int slot = (((ks * 4 + fg) ^ (c & 7)) * 8);
      const bf16x8 bhi = *reinterpret_cast<const bf16x8*>(&wl[0][c * 256 + slot]);
      const bf16x8 blo = *reinterpret_cast<const bf16x8*>(&wl[1][c * 256 + slot]);
      acc[n] = __builtin_amdgcn_mfma_f32_16x16x32_bf16(a, bhi, acc[n], 0, 0, 0);
      acc[n] = __builtin_amdgcn_mfma_f32_16x16x32_bf16(a, blo, acc[n], 0, 0, 0);
    }
  }

  float psS[4] = {0.f, 0.f, 0.f, 0.f}, psD[4] = {0.f, 0.f, 0.f, 0.f};
#pragma unroll
  for (int n = 0; n < 4; n++) {
    const int col = n * 16 + fr;
    const float as_ = att_s[col];
    const float ad_ = att_d[col];
#pragma unroll
    for (int r = 0; r < 4; r++) {
      psS[r] = fmaf(acc[n][r], as_, psS[r]);
      psD[r] = fmaf(acc[n][r], ad_, psD[r]);
    }
  }
#pragma unroll
  for (int r = 0; r < 4; r++)
#pragma unroll
    for (int o = 8; o > 0; o >>= 1) {
      psS[r] += __shfl_xor(psS[r], o, 64);
      psD[r] += __shfl_xor(psD[r], o, 64);
    }
  if (fr == 0) {
#pragma unroll
    for (int r = 0; r < 4; r++) {
      const int row = wrow0 + fg * 4 + r;
      if (row < N) { as2[row] = psS[r]; ad2[row] = psD[r]; }
    }
  }
#pragma unroll
  for (int r = 0; r < 4; r++) {
    const int row = wrow0 + fg * 4 + r;
    if (row < N) {
#pragma unroll
      for (int n = 0; n < 4; n++)
        h2b[(size_t)row * 64 + n * 16 + fr] = f2bf(acc[n][r]);
    }
  }
}

// ---- gather2 FUSED: lane-parallel weights -> wave LDS stash -> half-wave MLP=4 gather ----
__global__ __launch_bounds__(256) void gather2f_kernel(
    const unsigned short* __restrict__ h2b,
    const float* __restrict__ as2, const float* __restrict__ ad2,
    const float* __restrict__ b2, const int* __restrict__ row_start,
    const int* __restrict__ csr_src, float* __restrict__ h2, int N) {
  __shared__ float wbuf[4][64];
  __shared__ int   sbuf[4][64];
  const int lane = threadIdx.x & 63;
  const int wv   = threadIdx.x >> 6;
  const int v = blockIdx.x * 4 + wv;
  if (v >= N) return;
  const int half = lane >> 5;
  const int cl = lane & 31;
  const int rs = row_start[v], re = row_start[v + 1];
  const float adv = ad2[v];
  const float wself = __expf(lrelu(as2[v] + adv));
  float ax = 0.f, ay = 0.f;
  if (half == 0) {
    const unsigned int u = reinterpret_cast<const unsigned int*>(h2b + (size_t)v * 64)[cl];
    ax = wself * bf2f(u & 0xffffu);
    ay = wself * bf2f(u >> 16);
  }
  float denp = 0.f;
  for (int base = rs; base < re; base += 64) {
    const int cnt = min(64, re - base);
    int s = v;
    float w = 0.f;
    if (lane < cnt) {
      s = csr_src[base + lane];
      w = __expf(lrelu(as2[s] + adv));
      denp += w;
    }
    sbuf[wv][lane] = s;
    wbuf[wv][lane] = w;
    const int cntp = (cnt + 7) & ~7;
    for (int j = 0; j < cntp; j += 8) {
      const int b0 = j + half;
      const int s0 = sbuf[wv][b0],     s1 = sbuf[wv][b0 + 2];
      const int s2 = sbuf[wv][b0 + 4], s3 = sbuf[wv][b0 + 6];
      const float y0 = wbuf[wv][b0],     y1 = wbuf[wv][b0 + 2];
      const float y2 = wbuf[wv][b0 + 4], y3 = wbuf[wv][b0 + 6];
      const unsigned int f0 = reinterpret_cast<const unsigned int*>(h2b + (size_t)s0 * 64)[cl];
      const unsigned int f1 = reinterpret_cast<const unsigned int*>(h2b + (size_t)s1 * 64)[cl];
      const unsigned int f2 = reinterpret_cast<const unsigned int*>(h2b + (size_t)s2 * 64)[cl];
      const unsigned int f3 = reinterpret_cast<const unsigned int*>(h2b + (size_t)s3 * 64)[cl];
      ax = fmaf(y0, bf2f(f0 & 0xffffu), ax); ay = fmaf(y0, bf2f(f0 >> 16), ay);
      ax = fmaf(y1, bf2f(f1 & 0xffffu), ax); ay = fmaf(y1, bf2f(f1 >> 16), ay);
      ax = fmaf(y2, bf2f(f2 & 0xffffu), ax); ay = fmaf(y2, bf2f(f2 >> 16), ay);
      ax = fmaf(y3, bf2f(f3 & 0xffffu), ax); ay = fmaf(y3, bf2f(f3 >> 16), ay);
    }
  }
#pragma unroll
  for (int o = 32; o > 0; o >>= 1) denp += __shfl_xor(denp, o, 64);
  ax += __shfl_xor(ax, 32, 64);
  ay += __shfl_xor(ay, 32, 64);
  if (half == 0) {
    const float wi = 1.f / (denp + wself + EPS_SM);
    float2 o;
    o.x = elu1(ax * wi + b2[2 * cl]);
    o.y = elu1(ay * wi + b2[2 * cl + 1]);
    reinterpret_cast<float2*>(h2 + (size_t)v * 64)[cl] = o;
  }
}

// ---------------- mean-pool over sorted batch (MLP=4 row chunks) ----------------
__global__ __launch_bounds__(256) void pool_kernel(
    const float* __restrict__ h2, const int* __restrict__ batch,
    float* __restrict__ pooled, float* __restrict__ cntf, int N) {
  const int lane = threadIdx.x & 63;
  const int gw = blockIdx.x * 4 + (threadIdx.x >> 6);
  const int s = gw * 64;
  if (s >= N) return;
  const int e = min(s + 64, N);
  int cur = batch[s];
  float racc = 0.f;
  int rc = 0;
  auto flush = [&](int g) {
    atomicAdd(&pooled[(size_t)cur * 64 + lane], racc);
    if (lane == 0) atomicAdd(&cntf[cur], (float)rc);
    racc = 0.f; rc = 0; cur = g;
  };
  for (int v = s; v < e; v += 4) {
    const int m = min(4, e - v);
    const float r0 = h2[(size_t)v * 64 + lane];
    const float r1 = (m > 1) ? h2[(size_t)(v + 1) * 64 + lane] : 0.f;
    const float r2 = (m > 2) ? h2[(size_t)(v + 2) * 64 + lane] : 0.f;
    const float r3 = (m > 3) ? h2[(size_t)(v + 3) * 64 + lane] : 0.f;
    const int g0 = batch[v];
    const int g1 = (m > 1) ? batch[v + 1] : g0;
    const int g2 = (m > 2) ? batch[v + 2] : g1;
    const int g3 = (m > 3) ? batch[v + 3] : g2;
    if (g0 == cur && g3 == cur) {        // sorted => all in [cur]
      racc += (r0 + r1) + (r2 + r3);
      rc += m;
    } else {
      if (g0 != cur) flush(g0);
      racc += r0; rc++;
      if (m > 1) { if (g1 != cur) flush(g1); racc += r1; rc++; }
      if (m > 2) { if (g2 != cur) flush(g2); racc += r2; rc++; }
      if (m > 3) { if (g3 != cur) flush(g3); racc += r3; rc++; }
    }
  }
  atomicAdd(&pooled[(size_t)cur * 64 + lane], racc);
  if (lane == 0) atomicAdd(&cntf[cur], (float)rc);
}

// ---------------- classifier ----------------
__global__ __launch_bounds__(64) void final_kernel(
    const float* __restrict__ pooled, const float* __restrict__ cntf,
    const float* __restrict__ Wc, const float* __restrict__ bc, float* __restrict__ out) {
  const int g = threadIdx.x;
  float acc = 0.f;
  for (int c = 0; c < 64; c++) acc = fmaf(pooled[(size_t)g * 64 + c], Wc[c], acc);
  const float cnt = fmaxf(cntf[g], 1.0f);
  out[g] = acc / cnt + bc[0];
}

extern "C" void kernel_launch(void* const* d_in, const int* in_sizes, int n_in,
                              void* d_out, int out_size, void* d_ws, size_t ws_size,
                              hipStream_t stream) {
  const float* x     = (const float*)d_in[0];
  const int*   ei    = (const int*)d_in[1];
  const int*   batch = (const int*)d_in[2];
  const float* W1    = (const float*)d_in[3];
  const float* atts1 = (const float*)d_in[4];
  const float* attd1 = (const float*)d_in[5];
  const float* b1    = (const float*)d_in[6];
  const float* W2    = (const float*)d_in[7];
  const float* atts2 = (const float*)d_in[8];
  const float* attd2 = (const float*)d_in[9];
  const float* b2    = (const float*)d_in[10];
  const float* Wc    = (const float*)d_in[11];
  const float* bc    = (const float*)d_in[12];
  float* out = (float*)d_out;

  const int N = in_sizes[0] / IN_F;   // 50000
  const int E = in_sizes[1] / 2;      // 800000
  const int* src = ei;
  const int* dst = ei + E;
  const int NB = (N + 255) / 256;     // scan blocks
  const int NRT = (N + 255) / 256;    // gemm1 row tiles
  const int G1 = NRT * 2;             // gemm1 blocks in merged dispatch
  const int GH = (E + 511) / 512;     // hist blocks in merged dispatch

  char* ws = (char*)d_ws;
  size_t off = 0;
  auto take = [&](size_t bytes) -> void* {
    void* p = ws + off;
    off = (off + bytes + 255) & ~(size_t)255;
    return p;
  };
  unsigned short* h1b   = (unsigned short*)take((size_t)N * 256 * 2);
  unsigned short* hmidb = (unsigned short*)take((size_t)N * 256 * 2);
  unsigned short* h2b   = (unsigned short*)take((size_t)N * 64 * 2);
  unsigned short* wthi  = (unsigned short*)take((size_t)256 * 128 * 2);
  unsigned short* wtlo  = (unsigned short*)take((size_t)256 * 128 * 2);
  unsigned short* w2thi = (unsigned short*)take((size_t)64 * 256 * 2);
  unsigned short* w2tlo = (unsigned short*)take((size_t)64 * 256 * 2);
  float* as1      = (float*)take((size_t)N * 4 * sizeof(float));
  float* ad1      = (float*)take((size_t)N * 4 * sizeof(float));
  float* as2      = (float*)take((size_t)N * sizeof(float));
  float* ad2      = (float*)take((size_t)N * sizeof(float));
  int*   cnt      = (int*)take((size_t)N * sizeof(int));
  int*   row_start= (int*)take((size_t)(N + 1) * sizeof(int));
  int*   rank     = (int*)take((size_t)E * sizeof(int));
  int*   csr_src  = (int*)take((size_t)E * sizeof(int));
  int*   bsum     = (int*)take((size_t)NB * sizeof(int));
  int*   boff     = (int*)take((size_t)NB * sizeof(int));
  float* pooled   = (float*)take((size_t)GROUPS * 64 * sizeof(float));
  float* cntf     = (float*)take((size_t)GROUPS * sizeof(float));
  float* h2       = (float*)take((size_t)N * 64 * sizeof(float));

  hipMemsetAsync(cnt, 0, (size_t)N * sizeof(int), stream);
  hipMemsetAsync(pooled, 0, (size_t)GROUPS * 64 * sizeof(float), stream);
  hipMemsetAsync(cntf, 0, (size_t)GROUPS * sizeof(float), stream);

  // weight prep (single launch)
  prep_w_kernel<<<192, 256, 0, stream>>>(W1, wthi, wtlo, W2, w2thi, w2tlo);

  // conv1 linear (MFMA) + fused alpha + edge histogram (merged dispatch)
  gemm1_hist_kernel<<<G1 + GH, 512, 0, stream>>>(x, wthi, wtlo, atts1, attd1,
                                                 h1b, as1, ad1, N, dst, cnt, rank, E, G1);

  // CSR prefix-sum + atomic-free scatter
  block_reduce_kernel<<<NB, 256, 0, stream>>>(cnt, bsum, N);
  bsum_scan_kernel<<<1, 256, 0, stream>>>(bsum, boff, NB);
  block_scan_kernel<<<NB, 256, 0, stream>>>(cnt, boff, row_start, N);
  scatter_kernel<<<(E + 255) / 256, 256, 0, stream>>>(src, dst, row_start, rank, csr_src, E);

  // conv1 aggregate (weights fused in)
  gather1f_kernel<<<(N + 3) / 4, 256, 0, stream>>>(h1b, as1, ad1, b1, row_start, csr_src, hmidb, N);

  // conv2 (MFMA) + aggregate
  gemm2_mfma_kernel<<<(N + 127) / 128, 512, 0, stream>>>(hmidb, w2thi, w2tlo, atts2, attd2, h2b, as2, ad2, N);
  gather2f_kernel<<<(N + 3) / 4, 256, 0, stream>>>(h2b, as2, ad2, b2, row_start, csr_src, h2, N);

  // pooling + classifier
  pool_kernel<<<((N + 63) / 64 + 3) / 4, 256, 0, stream>>>(h2, batch, pooled, cntf, N);
  final_kernel<<<1, 64, 0, stream>>>(pooled, cntf, Wc, bc, out);

  (void)n_in; (void)out_size; (void)ws_size;
}